// Round 11
// baseline (447.755 us; speedup 1.0000x reference)
//
#include <hip/hip_runtime.h>
#include <hip/hip_bf16.h>

#define D_MODEL 256
#define NHEAD 8
#define DH 32
#define NLAYERS 4
#define DFF 1024
#define CC 2
#define DATA_DIM 128
#define PP 16
#define TT 64
#define BB 4
#define LL 1024
#define NEGV -1000000.0f

typedef __bf16 bf16_t;
typedef __bf16 bf16x8 __attribute__((ext_vector_type(8)));
typedef __bf16 bf16x4 __attribute__((ext_vector_type(4)));
typedef float v4f __attribute__((ext_vector_type(4)));

__device__ __forceinline__ bool my_isnan(float v) {
    unsigned u = __float_as_uint(v);
    return (u & 0x7fffffffu) > 0x7f800000u;
}

__device__ __forceinline__ void gld16(bf16_t* l, const bf16_t* g) {
    __builtin_amdgcn_global_load_lds(
        (const __attribute__((address_space(1))) void*)g,
        (__attribute__((address_space(3))) void*)l, 16, 0, 0);
}

// ---------------------------------------------------------------------------
// Combined fp32 -> bf16 conversion, 9 weight segments, 1 dispatch
// ---------------------------------------------------------------------------
__global__ void f2b_all_kernel(const float* __restrict__ s0, bf16_t* __restrict__ d0, int n0,
                               const float* __restrict__ s1, bf16_t* __restrict__ d1, int n1,
                               const float* __restrict__ s2, bf16_t* __restrict__ d2, int n2,
                               const float* __restrict__ s3, bf16_t* __restrict__ d3, int n3,
                               const float* __restrict__ s4, bf16_t* __restrict__ d4, int n4,
                               const float* __restrict__ s5, bf16_t* __restrict__ d5, int n5,
                               const float* __restrict__ s6, bf16_t* __restrict__ d6, int n6,
                               const float* __restrict__ s7, bf16_t* __restrict__ d7, int n7,
                               const float* __restrict__ s8, bf16_t* __restrict__ d8, int n8) {
    int i = (blockIdx.x * 256 + threadIdx.x) * 4;
    const float* s;
    bf16_t* d;
    if (i < n0) { s = s0; d = d0; }
    else if ((i -= n0) < n1) { s = s1; d = d1; }
    else if ((i -= n1) < n2) { s = s2; d = d2; }
    else if ((i -= n2) < n3) { s = s3; d = d3; }
    else if ((i -= n3) < n4) { s = s4; d = d4; }
    else if ((i -= n4) < n5) { s = s5; d = d5; }
    else if ((i -= n5) < n6) { s = s6; d = d6; }
    else if ((i -= n6) < n7) { s = s7; d = d7; }
    else if ((i -= n7) < n8) { s = s8; d = d8; }
    else return;
    float4 v = *(const float4*)(s + i);
    bf16x4 o = {(bf16_t)v.x, (bf16_t)v.y, (bf16_t)v.z, (bf16_t)v.w};
    *(bf16x4*)(d + i) = o;
}

// ---------------------------------------------------------------------------
// Prep: frame_pad detection + temporal embedding MLP
// ---------------------------------------------------------------------------
__global__ void prep_frame_kernel(const float* __restrict__ img,
                                  const float* __restrict__ acq,
                                  const float* __restrict__ t_w1, const float* __restrict__ t_b1,
                                  const float* __restrict__ t_w2, const float* __restrict__ t_b2,
                                  const float* __restrict__ t_w3, const float* __restrict__ t_b3,
                                  float* __restrict__ temb, int* __restrict__ framepad) {
    int f = blockIdx.x;
    int tid = threadIdx.x;
    __shared__ float h1[64];
    __shared__ float h2[128];
    __shared__ int sAll;
    if (tid == 0) sAll = 1;
    __syncthreads();
    const float* fr = img + (size_t)f * (CC * 32 * 32);
    bool allpad = true;
    #pragma unroll
    for (int i = 0; i < 8; ++i) {
        float v = fr[tid + i * 256];
        allpad = allpad && (v == -9999.0f);
    }
    if (!allpad) sAll = 0;
    __syncthreads();
    if (tid == 0) framepad[f] = sAll;

    float t_in = acq[f];
    if (my_isnan(t_in)) t_in = 0.0f;
    if (tid < 64) h1[tid] = fmaxf(t_w1[tid] * t_in + t_b1[tid], 0.0f);
    __syncthreads();
    if (tid < 128) {
        float a = t_b2[tid];
        #pragma unroll 8
        for (int j = 0; j < 64; ++j) a += t_w2[tid * 64 + j] * h1[j];
        h2[tid] = fmaxf(a, 0.0f);
    }
    __syncthreads();
    {
        float a = t_b3[tid];
        #pragma unroll 8
        for (int j = 0; j < 128; ++j) a += t_w3[tid * 128 + j] * h2[j];
        temb[(size_t)f * D_MODEL + tid] = a;
    }
}

// ---------------------------------------------------------------------------
// Patchify: img -> xpb (bf16 4096x128), masked_rows, kmaskf.
// ---------------------------------------------------------------------------
__global__ __launch_bounds__(256) void patchify_kernel(
    const float* __restrict__ img, const float* __restrict__ nan_token,
    const int* __restrict__ framepad,
    bf16_t* __restrict__ xpb, int* __restrict__ masked_rows,
    float* __restrict__ kmaskf) {
    int tid = threadIdx.x;
    int token = blockIdx.x * 2 + (tid >> 7);
    int dd = tid & 127;
    int l = token & 1023, b = token >> 10;
    int t = l >> 4, p = l & 15;
    int c = dd >> 6, pr = (dd >> 3) & 7, pc = dd & 7;
    int hh = (p >> 2) * 8 + pr, ww = (p & 3) * 8 + pc;
    float v = img[(((size_t)(b * TT + t) * CC + c) * 32 + hh) * 32 + ww];
    bool nanp = my_isnan(v);
    if (nanp) v = fminf(fmaxf(nan_token[c], -10.0f), 10.0f);
    v = fminf(fmaxf(v, -10.0f), 10.0f);
    xpb[(size_t)token * DATA_DIM + dd] = (bf16_t)v;

    __shared__ int wAll[4];
    unsigned long long bal = __ballot(nanp);
    if ((tid & 63) == 0) wAll[tid >> 6] = (bal == 0xFFFFFFFFFFFFFFFFull) ? 1 : 0;
    __syncthreads();
    if (tid < 2) {
        int tk = blockIdx.x * 2 + tid;
        int allnan = wAll[tid * 2] & wAll[tid * 2 + 1];
        int fp = framepad[tk >> 4];
        masked_rows[tk] = allnan | fp;
        kmaskf[tk] = fp ? NEGV : 0.0f;
    }
}

// ---------------------------------------------------------------------------
// Embed GEMM: z = xp @ emb_w^T + emb_b + spatial + temb (pad override).
// ---------------------------------------------------------------------------
__global__ __launch_bounds__(256) void embed_gemm(
    const bf16_t* __restrict__ X, const bf16_t* __restrict__ W,
    const float* __restrict__ emb_b, const float* __restrict__ spatial,
    const float* __restrict__ temb, const float* __restrict__ pad_embed,
    const int* __restrict__ framepad,
    float* __restrict__ z, bf16_t* __restrict__ zb) {
    __shared__ __align__(16) bf16_t Xs[128 * 32];
    __shared__ __align__(16) bf16_t Ws[64 * 32];
    int tid = threadIdx.x;
    int wave = tid >> 6, lane = tid & 63;
    int quad = lane >> 4, l16 = lane & 15;
    int m0 = blockIdx.y * 128, n0 = blockIdx.x * 64;
    const int K = DATA_DIM, N = D_MODEL;

    v4f acc[2][4];
    #pragma unroll
    for (int i = 0; i < 2; ++i)
        #pragma unroll
        for (int j = 0; j < 4; ++j) acc[i][j] = (v4f){0.f, 0.f, 0.f, 0.f};

    int sr = tid >> 2, ss = tid & 3;
    for (int k0 = 0; k0 < K; k0 += 32) {
        gld16(Xs + tid * 8, X + (size_t)(m0 + sr) * K + k0 + ss * 8);
        gld16(Xs + 2048 + tid * 8, X + (size_t)(m0 + 64 + sr) * K + k0 + ss * 8);
        gld16(Ws + tid * 8, W + (size_t)(n0 + sr) * K + k0 + ss * 8);
        __syncthreads();
        bf16x8 af0 = *(const bf16x8*)(Xs + (wave * 32 + l16) * 32 + quad * 8);
        bf16x8 af1 = *(const bf16x8*)(Xs + (wave * 32 + 16 + l16) * 32 + quad * 8);
        #pragma unroll
        for (int nt = 0; nt < 4; ++nt) {
            bf16x8 bfr = *(const bf16x8*)(Ws + (nt * 16 + l16) * 32 + quad * 8);
            acc[0][nt] = __builtin_amdgcn_mfma_f32_16x16x32_bf16(af0, bfr, acc[0][nt], 0, 0, 0);
            acc[1][nt] = __builtin_amdgcn_mfma_f32_16x16x32_bf16(af1, bfr, acc[1][nt], 0, 0, 0);
        }
        __syncthreads();
    }

    #pragma unroll
    for (int mt = 0; mt < 2; ++mt)
        #pragma unroll
        for (int nt = 0; nt < 4; ++nt) {
            int col = n0 + nt * 16 + l16;
            #pragma unroll
            for (int reg = 0; reg < 4; ++reg) {
                int row = m0 + wave * 32 + mt * 16 + quad * 4 + reg;
                int frame = row >> 4, p = row & 15;
                float v;
                if (framepad[frame]) {
                    v = pad_embed[col];
                } else {
                    v = acc[mt][nt][reg] + emb_b[col] + spatial[p * N + col]
                      + temb[(size_t)frame * N + col];
                }
                z[(size_t)row * N + col] = v;
                zb[(size_t)row * N + col] = (bf16_t)v;
            }
        }
}

// ---------------------------------------------------------------------------
// MFMA GEMM: BM=128, BN=64, BK=32. MODE 1: bf16 out. MODE 2: qkv split.
// ---------------------------------------------------------------------------
template <int MODE, int RELU>
__global__ __launch_bounds__(256) void gemm_mfma(
    const bf16_t* __restrict__ X, const bf16_t* __restrict__ W,
    const float* __restrict__ bias, bf16_t* __restrict__ Y,
    bf16_t* __restrict__ Vt, int M, int N, int K) {
    __shared__ __align__(16) bf16_t Xs[128 * 32];
    __shared__ __align__(16) bf16_t Ws[64 * 32];
    int tid = threadIdx.x;
    int wave = tid >> 6, lane = tid & 63;
    int quad = lane >> 4, l16 = lane & 15;
    int m0 = blockIdx.y * 128, n0 = blockIdx.x * 64;

    v4f acc[2][4];
    #pragma unroll
    for (int i = 0; i < 2; ++i)
        #pragma unroll
        for (int j = 0; j < 4; ++j) acc[i][j] = (v4f){0.f, 0.f, 0.f, 0.f};

    int sr = tid >> 2, ss = tid & 3;
    for (int k0 = 0; k0 < K; k0 += 32) {
        gld16(Xs + tid * 8, X + (size_t)(m0 + sr) * K + k0 + ss * 8);
        gld16(Xs + 2048 + tid * 8, X + (size_t)(m0 + 64 + sr) * K + k0 + ss * 8);
        gld16(Ws + tid * 8, W + (size_t)(n0 + sr) * K + k0 + ss * 8);
        __syncthreads();
        bf16x8 af0 = *(const bf16x8*)(Xs + (wave * 32 + l16) * 32 + quad * 8);
        bf16x8 af1 = *(const bf16x8*)(Xs + (wave * 32 + 16 + l16) * 32 + quad * 8);
        #pragma unroll
        for (int nt = 0; nt < 4; ++nt) {
            bf16x8 bfr = *(const bf16x8*)(Ws + (nt * 16 + l16) * 32 + quad * 8);
            acc[0][nt] = __builtin_amdgcn_mfma_f32_16x16x32_bf16(af0, bfr, acc[0][nt], 0, 0, 0);
            acc[1][nt] = __builtin_amdgcn_mfma_f32_16x16x32_bf16(af1, bfr, acc[1][nt], 0, 0, 0);
        }
        __syncthreads();
    }

    if constexpr (MODE == 1) {
        #pragma unroll
        for (int mt = 0; mt < 2; ++mt)
            #pragma unroll
            for (int nt = 0; nt < 4; ++nt) {
                int col = n0 + nt * 16 + l16;
                float bv = bias[col];
                #pragma unroll
                for (int reg = 0; reg < 4; ++reg) {
                    int row = m0 + wave * 32 + mt * 16 + quad * 4 + reg;
                    float v = acc[mt][nt][reg] + bv;
                    if (RELU) v = fmaxf(v, 0.0f);
                    Y[(size_t)row * N + col] = (bf16_t)v;
                }
            }
    } else {  // MODE 2
        if (n0 < 512) {
            #pragma unroll
            for (int mt = 0; mt < 2; ++mt)
                #pragma unroll
                for (int nt = 0; nt < 4; ++nt) {
                    int col = n0 + nt * 16 + l16;
                    float bv = bias[col];
                    #pragma unroll
                    for (int reg = 0; reg < 4; ++reg) {
                        int row = m0 + wave * 32 + mt * 16 + quad * 4 + reg;
                        float v = acc[mt][nt][reg] + bv;
                        Y[(size_t)row * 768 + col] = (bf16_t)v;
                    }
                }
        } else {
            __shared__ __align__(16) bf16_t VT[64 * 136];
            #pragma unroll
            for (int mt = 0; mt < 2; ++mt)
                #pragma unroll
                for (int nt = 0; nt < 4; ++nt) {
                    int cl = nt * 16 + l16;
                    float bv = bias[n0 + cl];
                    #pragma unroll
                    for (int reg = 0; reg < 4; ++reg) {
                        int rl = wave * 32 + mt * 16 + quad * 4 + reg;
                        VT[cl * 136 + rl] = (bf16_t)(acc[mt][nt][reg] + bv);
                    }
                }
            __syncthreads();
            int b = m0 >> 10, l0m = m0 & 1023;
            int cl = tid >> 2;
            int rbase = (tid & 3) * 8;
            int cg = n0 + cl - 512;
            int h = cg >> 5, d = cg & 31;
            bf16_t* dst = Vt + (((size_t)(b * NHEAD + h)) * DH + d) * LL + l0m;
            #pragma unroll
            for (int u = 0; u < 4; ++u)
                *(uint4*)(dst + rbase + u * 32) = *(const uint4*)(VT + cl * 136 + rbase + u * 32);
        }
    }
}

// ---------------------------------------------------------------------------
// Fused GEMM + residual + LayerNorm, BM=16 / BN=256 (grid = M/16 = 256):
//   z = LN(z + X@W^T + bias) * lnw + lnb ; zb = bf16(z).
// 4 waves; all waves share the 16 rows, each covers 64 cols.
// Row stats: in-thread over 4 col-tiles -> 4-hop shfl within 16-lane group ->
// 4-wave LDS combine (one barrier). var = E[x^2]-mean^2.
// ---------------------------------------------------------------------------
__global__ __launch_bounds__(256) void gemm_ln16(
    const bf16_t* __restrict__ X, const bf16_t* __restrict__ W,
    const float* __restrict__ bias,
    float* __restrict__ z, const float* __restrict__ lnw, const float* __restrict__ lnb,
    bf16_t* __restrict__ zb, int K) {
    __shared__ __align__(16) bf16_t Xs[16 * 32];
    __shared__ __align__(16) bf16_t Ws[256 * 32];
    __shared__ float redS[4][16];
    __shared__ float redQ[4][16];
    int tid = threadIdx.x;
    int wave = tid >> 6, lane = tid & 63;
    int quad = lane >> 4, l16 = lane & 15;
    int m0 = blockIdx.x * 16;

    v4f acc[4];
    #pragma unroll
    for (int j = 0; j < 4; ++j) acc[j] = (v4f){0.f, 0.f, 0.f, 0.f};

    for (int k0 = 0; k0 < K; k0 += 32) {
        if (tid < 64)
            gld16(Xs + tid * 8, X + (size_t)(m0 + (tid >> 2)) * K + k0 + (tid & 3) * 8);
        #pragma unroll
        for (int i = 0; i < 4; ++i) {
            int idx = tid + i * 256;
            gld16(Ws + idx * 8, W + (size_t)(idx >> 2) * K + k0 + (idx & 3) * 8);
        }
        __syncthreads();
        bf16x8 af = *(const bf16x8*)(Xs + l16 * 32 + quad * 8);
        #pragma unroll
        for (int nt = 0; nt < 4; ++nt) {
            bf16x8 bfr = *(const bf16x8*)(Ws + (wave * 64 + nt * 16 + l16) * 32 + quad * 8);
            acc[nt] = __builtin_amdgcn_mfma_f32_16x16x32_bf16(af, bfr, acc[nt], 0, 0, 0);
        }
        __syncthreads();
    }

    // v = acc + bias + residual
    float v[4][4];
    #pragma unroll
    for (int nt = 0; nt < 4; ++nt) {
        int col = wave * 64 + nt * 16 + l16;
        float bv = bias[col];
        #pragma unroll
        for (int reg = 0; reg < 4; ++reg) {
            int row = m0 + quad * 4 + reg;
            v[nt][reg] = acc[nt][reg] + bv + z[(size_t)row * D_MODEL + col];
        }
    }

    // per-row partial sums within this wave's 64 cols
    float s[4], q[4];
    #pragma unroll
    for (int reg = 0; reg < 4; ++reg) {
        float ss = 0.0f, qq = 0.0f;
        #pragma unroll
        for (int nt = 0; nt < 4; ++nt) {
            ss += v[nt][reg];
            qq += v[nt][reg] * v[nt][reg];
        }
        s[reg] = ss;
        q[reg] = qq;
    }
    #pragma unroll
    for (int off = 1; off < 16; off <<= 1)
        #pragma unroll
        for (int reg = 0; reg < 4; ++reg) {
            s[reg] += __shfl_xor(s[reg], off);
            q[reg] += __shfl_xor(q[reg], off);
        }
    if (l16 == 0) {
        #pragma unroll
        for (int reg = 0; reg < 4; ++reg) {
            redS[wave][quad * 4 + reg] = s[reg];
            redQ[wave][quad * 4 + reg] = q[reg];
        }
    }
    __syncthreads();

    #pragma unroll
    for (int reg = 0; reg < 4; ++reg) {
        int rloc = quad * 4 + reg;
        float S = redS[0][rloc] + redS[1][rloc] + redS[2][rloc] + redS[3][rloc];
        float Q = redQ[0][rloc] + redQ[1][rloc] + redQ[2][rloc] + redQ[3][rloc];
        float mean = S * (1.0f / D_MODEL);
        float var = Q * (1.0f / D_MODEL) - mean * mean;
        float inv = 1.0f / sqrtf(var + 1e-5f);
        int row = m0 + rloc;
        #pragma unroll
        for (int nt = 0; nt < 4; ++nt) {
            int col = wave * 64 + nt * 16 + l16;
            float o = (v[nt][reg] - mean) * inv * lnw[col] + lnb[col];
            z[(size_t)row * D_MODEL + col] = o;
            zb[(size_t)row * D_MODEL + col] = (bf16_t)o;
        }
    }
}

// ---------------------------------------------------------------------------
// Flash attention, bf16 MFMA. Fixed-m softmax, XCD-pinned, 128-key chunks,
// LDS dbuf + register prefetch, 1 barrier/chunk.
// ---------------------------------------------------------------------------
__global__ __launch_bounds__(256) void attn_mfma(
    const bf16_t* __restrict__ qkvb, const bf16_t* __restrict__ Vt,
    const int* __restrict__ masked_rows, const float* __restrict__ kmaskf,
    bf16_t* __restrict__ Ob) {
    __shared__ __align__(16) bf16_t Ks[2][128 * 40];
    __shared__ __align__(16) bf16_t Vs[2][32 * 136];
    __shared__ __align__(16) float  Kms[2][128];
    __shared__ __align__(16) bf16_t Ps[4][16 * 136];

    int tid = threadIdx.x;
    int wave = tid >> 6, lane = tid & 63;
    int quad = lane >> 4, l16 = lane & 15;
    int bid = blockIdx.x;
    int h = bid & 7, b = (bid >> 3) & 3, qt = bid >> 5;
    int q0 = qt * 64 + wave * 16;
    const float scale = 0.17677669529663687f;

    bf16x8 qf = *(const bf16x8*)(qkvb + ((size_t)(b * LL) + q0 + l16) * 768 + h * DH + quad * 8);

    int mq[4];
    #pragma unroll
    for (int reg = 0; reg < 4; ++reg) mq[reg] = masked_rows[b * LL + q0 + quad * 4 + reg];

    float lrun[4];
    v4f oacc[2];
    #pragma unroll
    for (int reg = 0; reg < 4; ++reg) lrun[reg] = 0.0f;
    oacc[0] = (v4f){0.f, 0.f, 0.f, 0.f};
    oacc[1] = (v4f){0.f, 0.f, 0.f, 0.f};

    int kr = tid >> 1, kh = (tid & 1) * 16;
    int vd = tid >> 3, vs0 = (tid & 7) * 8;
    const bf16_t* Kbase = qkvb + (size_t)(b * LL) * 768 + 256 + h * DH;
    const bf16_t* Vbase = Vt + (((size_t)(b * NHEAD + h)) * DH) * LL;
    const float* kmbase = kmaskf + b * LL;

    uint4 ka, kb, va, vb;
    float kmg;
    #define LOADC(c)                                                            \
        do {                                                                    \
            int _k0 = (c) * 128;                                                \
            ka = *(const uint4*)(Kbase + (size_t)(_k0 + kr) * 768 + kh);        \
            kb = *(const uint4*)(Kbase + (size_t)(_k0 + kr) * 768 + kh + 8);    \
            va = *(const uint4*)(Vbase + (size_t)vd * LL + _k0 + vs0);          \
            vb = *(const uint4*)(Vbase + (size_t)vd * LL + _k0 + 64 + vs0);     \
            kmg = (tid < 128) ? kmbase[_k0 + tid] : 0.0f;                       \
        } while (0)
    #define WRITEBUF(buf)                                                       \
        do {                                                                    \
            *(uint4*)(Ks[(buf)] + kr * 40 + kh) = ka;                           \
            *(uint4*)(Ks[(buf)] + kr * 40 + kh + 8) = kb;                       \
            *(uint4*)(Vs[(buf)] + vd * 136 + vs0) = va;                         \
            *(uint4*)(Vs[(buf)] + vd * 136 + 64 + vs0) = vb;                    \
            if (tid < 128) Kms[(buf)][tid] = kmg;                               \
        } while (0)

    LOADC(0);
    WRITEBUF(0);
    LOADC(1);

    bf16_t* Pw = Ps[wave];
    for (int c = 0; c < 8; ++c) {
        __syncthreads();
        int cur = c & 1;
        if (c + 1 < 8) WRITEBUF(cur ^ 1);
        if (c + 2 < 8) LOADC(c + 2);

        int k0 = c * 128;
        const bf16_t* Kc = Ks[cur];
        const bf16_t* Vc = Vs[cur];
        const float* kmc = Kms[cur];

        v4f sf[8];
        #pragma unroll
        for (int nt = 0; nt < 8; ++nt) {
            bf16x8 kf = *(const bf16x8*)(Kc + (nt * 16 + l16) * 40 + quad * 8);
            v4f zf = (v4f){0.f, 0.f, 0.f, 0.f};
            sf[nt] = __builtin_amdgcn_mfma_f32_16x16x32_bf16(qf, kf, zf, 0, 0, 0);
        }

        #pragma unroll
        for (int nt = 0; nt < 8; ++nt) {
            int kg = k0 + nt * 16 + l16;
            float km = kmc[nt * 16 + l16];
            #pragma unroll
            for (int reg = 0; reg < 4; ++reg) {
                float v = sf[nt][reg] * scale + km;
                if (mq[reg] && (q0 + quad * 4 + reg != kg)) v += NEGV;
                float p = __expf(v);
                lrun[reg] += p;
                Pw[(quad * 4 + reg) * 136 + nt * 16 + l16] = (bf16_t)p;
            }
        }

        #pragma unroll
        for (int kt = 0; kt < 4; ++kt) {
            bf16x8 pf = *(const bf16x8*)(Pw + l16 * 136 + kt * 32 + quad * 8);
            #pragma unroll
            for (int nt2 = 0; nt2 < 2; ++nt2) {
                bf16x8 vf = *(const bf16x8*)(Vc + (nt2 * 16 + l16) * 136 + kt * 32 + quad * 8);
                oacc[nt2] = __builtin_amdgcn_mfma_f32_16x16x32_bf16(pf, vf, oacc[nt2], 0, 0, 0);
            }
        }
    }
    #undef LOADC
    #undef WRITEBUF

    #pragma unroll
    for (int off = 1; off < 16; off <<= 1)
        #pragma unroll
        for (int reg = 0; reg < 4; ++reg) lrun[reg] += __shfl_xor(lrun[reg], off);

    #pragma unroll
    for (int nt2 = 0; nt2 < 2; ++nt2)
        #pragma unroll
        for (int reg = 0; reg < 4; ++reg) {
            size_t row = (size_t)(b * LL) + q0 + quad * 4 + reg;
            Ob[row * 256 + h * DH + nt2 * 16 + l16] = (bf16_t)(oacc[nt2][reg] / lrun[reg]);
        }
}

// ---------------------------------------------------------------------------
// Head stage 1 (MFMA): both heads, grid.y = head.
// ---------------------------------------------------------------------------
__global__ __launch_bounds__(256) void head_h_kernel(
    const bf16_t* __restrict__ zb, const bf16_t* __restrict__ W1b,
    const float* __restrict__ mean_b1, const float* __restrict__ lv_b1,
    bf16_t* __restrict__ hb) {
    __shared__ __align__(16) bf16_t Xs[64 * 32];
    __shared__ __align__(16) bf16_t Ws[64 * 32];
    int tid = threadIdx.x;
    int wave = tid >> 6, lane = tid & 63;
    int quad = lane >> 4, l16 = lane & 15;
    int head = blockIdx.y;
    int n0 = blockIdx.x * 64;
    const bf16_t* W1h = W1b + (size_t)head * DFF * D_MODEL;
    const float* B1f = head ? lv_b1 : mean_b1;
    bf16_t* hbh = hb + (size_t)head * 64 * DFF;

    v4f acc[4];
    #pragma unroll
    for (int j = 0; j < 4; ++j) acc[j] = (v4f){0.f, 0.f, 0.f, 0.f};

    int sr = tid >> 2, ss = tid & 3;
    int gb = sr >> 4, gp = sr & 15;
    const bf16_t* xrow = zb + ((size_t)(gb * LL + (TT - 1) * PP + gp)) * D_MODEL;
    for (int k0 = 0; k0 < D_MODEL; k0 += 32) {
        gld16(Xs + tid * 8, xrow + k0 + ss * 8);
        gld16(Ws + tid * 8, W1h + (size_t)(n0 + sr) * D_MODEL + k0 + ss * 8);
        __syncthreads();
        bf16x8 af = *(const bf16x8*)(Xs + (wave * 16 + l16) * 32 + quad * 8);
        #pragma unroll
        for (int nt = 0; nt < 4; ++nt) {
            bf16x8 bfr = *(const bf16x8*)(Ws + (nt * 16 + l16) * 32 + quad * 8);
            acc[nt] = __builtin_amdgcn_mfma_f32_16x16x32_bf16(af, bfr, acc[nt], 0, 0, 0);
        }
        __syncthreads();
    }

    #pragma unroll
    for (int nt = 0; nt < 4; ++nt) {
        int col = n0 + nt * 16 + l16;
        float bv = B1f[col];
        #pragma unroll
        for (int reg = 0; reg < 4; ++reg) {
            int row = wave * 16 + quad * 4 + reg;
            hbh[(size_t)row * DFF + col] = (bf16_t)fmaxf(acc[nt][reg] + bv, 0.0f);
        }
    }
}

// ---------------------------------------------------------------------------
// Head stage 2: out = clip(h @ W2^T + B2) + unpatch scatter.
// ---------------------------------------------------------------------------
__global__ __launch_bounds__(256) void head_out_kernel(
    const bf16_t* __restrict__ hb, const bf16_t* __restrict__ W2b,
    const float* __restrict__ mean_b2, const float* __restrict__ lv_b2,
    float* __restrict__ out) {
    __shared__ __align__(16) bf16_t hrow[DFF];
    int tid = threadIdx.x;
    int bid = blockIdx.x;
    int head = bid >> 7, rr = (bid >> 1) & 63, half = bid & 1;
    int b = rr >> 4, p = rr & 15;

    if (tid < 128)
        *(uint4*)(hrow + tid * 8) =
            *(const uint4*)(hb + ((size_t)head * 64 + rr) * DFF + tid * 8);
    __syncthreads();

    int ol = tid >> 2, quarter = tid & 3;
    int o = half * 64 + ol;
    const bf16_t* wrow = W2b + ((size_t)head * DATA_DIM + o) * DFF + quarter * 256;
    const bf16_t* hseg = hrow + quarter * 256;
    float acc = 0.0f;
    #pragma unroll 8
    for (int j = 0; j < 32; ++j) {
        bf16x8 w = *(const bf16x8*)(wrow + j * 8);
        bf16x8 hv = *(const bf16x8*)(hseg + j * 8);
        #pragma unroll
        for (int e = 0; e < 8; ++e) acc += (float)w[e] * (float)hv[e];
    }
    acc += __shfl_xor(acc, 1);
    acc += __shfl_xor(acc, 2);
    if (quarter == 0) {
        const float* B2 = head ? lv_b2 : mean_b2;
        float hi = head ? 5.0f : 10.0f;
        float v = fminf(fmaxf(acc + B2[o], -10.0f), hi);
        int c = o >> 6;
        int pr = (o >> 3) & 7, pc = o & 7;
        int hh = (p >> 2) * 8 + pr, ww = (p & 3) * 8 + pc;
        out[(size_t)head * 8192 + ((size_t)(b * CC + c)) * 1024 + hh * 32 + ww] = v;
    }
}

// ---------------------------------------------------------------------------
extern "C" void kernel_launch(void* const* d_in, const int* in_sizes, int n_in,
                              void* d_out, int out_size, void* d_ws, size_t ws_size,
                              hipStream_t stream) {
    const float* img        = (const float*)d_in[0];
    const float* acq        = (const float*)d_in[1];
    const float* nan_token  = (const float*)d_in[2];
    const float* pad_embed  = (const float*)d_in[3];
    const float* emb_w      = (const float*)d_in[4];
    const float* emb_b      = (const float*)d_in[5];
    const float* spatial    = (const float*)d_in[6];
    const float* t_w1       = (const float*)d_in[7];
    const float* t_b1       = (const float*)d_in[8];
    const float* t_w2       = (const float*)d_in[9];
    const float* t_b2       = (const float*)d_in[10];
    const float* t_w3       = (const float*)d_in[11];
    const float* t_b3       = (const float*)d_in[12];
    const float* in_proj_w  = (const float*)d_in[13];
    const float* in_proj_b  = (const float*)d_in[14];
    const float* out_proj_w = (const float*)d_in[15];
    const float* out_proj_b = (const float*)d_in[16];
    const float* lin1_w     = (const float*)d_in[17];
    const float* lin1_b     = (const float*)d_in[18];
    const float* lin2_w     = (const float*)d_in[19];
    const float* lin2_b     = (const float*)d_in[20];
    const float* norm1_w    = (const float*)d_in[21];
    const float* norm1_b    = (const float*)d_in[22];
    const float* norm2_w    = (const float*)d_in[23];
    const float* norm2_b    = (const float*)d_in[24];
    const float* mean_w1    = (const float*)d_in[25];
    const float* mean_b1    = (const float*)d_in[26];
    const float* mean_w2    = (const float*)d_in[27];
    const float* mean_b2    = (const float*)d_in[28];
    const float* lv_w1      = (const float*)d_in[29];
    const float* lv_b1      = (const float*)d_in[30];
    const float* lv_w2      = (const float*)d_in[31];
    const float* lv_b2      = (const float*)d_in[32];

    const int M = BB * LL;   // 4096 tokens

    // ---- workspace carve-up ----
    char* wsb = (char*)d_ws;
    float* z       = (float*)wsb;                    wsb += (size_t)M * D_MODEL * 4;
    float* temb    = (float*)wsb;                    wsb += (size_t)BB * TT * D_MODEL * 4;
    float* kmaskf  = (float*)wsb;                    wsb += M * 4;
    int* framepad  = (int*)wsb;                      wsb += BB * TT * 4;
    int* masked    = (int*)wsb;                      wsb += M * 4;
    wsb = (char*)(((uintptr_t)wsb + 255) & ~(uintptr_t)255);
    bf16_t* zb     = (bf16_t*)wsb;                   wsb += (size_t)M * D_MODEL * 2;
    bf16_t* xpb    = (bf16_t*)wsb;                   wsb += (size_t)M * DATA_DIM * 2;
    bf16_t* qkvb   = (bf16_t*)wsb;                   wsb += (size_t)M * 768 * 2;
    bf16_t* VtG    = (bf16_t*)wsb;                   wsb += (size_t)M * D_MODEL * 2;
    bf16_t* attnb  = (bf16_t*)wsb;                   wsb += (size_t)M * D_MODEL * 2;
    bf16_t* ff1b   = (bf16_t*)wsb;                   wsb += (size_t)M * DFF * 2;
    bf16_t* inb    = (bf16_t*)wsb;                   wsb += (size_t)NLAYERS * 768 * D_MODEL * 2;
    bf16_t* outb   = (bf16_t*)wsb;                   wsb += (size_t)NLAYERS * D_MODEL * D_MODEL * 2;
    bf16_t* l1b    = (bf16_t*)wsb;                   wsb += (size_t)NLAYERS * DFF * D_MODEL * 2;
    bf16_t* l2b    = (bf16_t*)wsb;                   wsb += (size_t)NLAYERS * D_MODEL * DFF * 2;
    bf16_t* embwb  = (bf16_t*)wsb;                   wsb += (size_t)D_MODEL * DATA_DIM * 2;
    bf16_t* w1b    = (bf16_t*)wsb;                   wsb += (size_t)2 * DFF * D_MODEL * 2;
    bf16_t* w2b    = (bf16_t*)wsb;                   wsb += (size_t)2 * DATA_DIM * DFF * 2;
    bf16_t* hb     = (bf16_t*)wsb;                   wsb += (size_t)2 * 64 * DFF * 2;

    float* outF = (float*)d_out;

    // ---- weight conversion (1 dispatch, 9 segments) ----
    {
        int n1 = NLAYERS * 768 * D_MODEL;
        int n2 = NLAYERS * D_MODEL * D_MODEL;
        int n3 = NLAYERS * DFF * D_MODEL;
        int n4 = NLAYERS * D_MODEL * DFF;
        int n5 = D_MODEL * DATA_DIM;
        int n6 = DFF * D_MODEL;
        int n7 = DFF * D_MODEL;
        int n8 = DATA_DIM * DFF;
        int n9 = DATA_DIM * DFF;
        int tot = n1 + n2 + n3 + n4 + n5 + n6 + n7 + n8 + n9;
        f2b_all_kernel<<<(tot / 4 + 255) / 256, 256, 0, stream>>>(
            in_proj_w, inb, n1, out_proj_w, outb, n2, lin1_w, l1b, n3,
            lin2_w, l2b, n4, emb_w, embwb, n5,
            mean_w1, w1b, n6, lv_w1, w1b + (size_t)DFF * D_MODEL, n7,
            mean_w2, w2b, n8, lv_w2, w2b + (size_t)DATA_DIM * DFF, n9);
    }

    // ---- prep + patchify + embed GEMM ----
    prep_frame_kernel<<<BB * TT, 256, 0, stream>>>(img, acq, t_w1, t_b1, t_w2, t_b2,
                                                   t_w3, t_b3, temb, framepad);
    patchify_kernel<<<M / 2, 256, 0, stream>>>(img, nan_token, framepad, xpb, masked, kmaskf);
    embed_gemm<<<dim3(D_MODEL / 64, M / 128), 256, 0, stream>>>(
        xpb, embwb, emb_b, spatial, temb, pad_embed, framepad, z, zb);

    // ---- transformer layers (5 dispatches each) ----
    for (int l = 0; l < NLAYERS; ++l) {
        gemm_mfma<2, 0><<<dim3(768 / 64, M / 128), 256, 0, stream>>>(
            zb, inb + (size_t)l * 768 * D_MODEL, in_proj_b + (size_t)l * 768,
            qkvb, VtG, M, 768, D_MODEL);
        attn_mfma<<<BB * NHEAD * (LL / 64), 256, 0, stream>>>(qkvb, VtG, masked, kmaskf, attnb);
        // out_proj + residual + LN1 (fused, grid 256)
        gemm_ln16<<<M / 16, 256, 0, stream>>>(
            attnb, outb + (size_t)l * D_MODEL * D_MODEL, out_proj_b + (size_t)l * D_MODEL,
            z, norm1_w + l * D_MODEL, norm1_b + l * D_MODEL, zb, D_MODEL);
        gemm_mfma<1, 1><<<dim3(DFF / 64, M / 128), 256, 0, stream>>>(
            zb, l1b + (size_t)l * DFF * D_MODEL, lin1_b + (size_t)l * DFF,
            ff1b, nullptr, M, DFF, D_MODEL);
        // ff2 + residual + LN2 (fused, grid 256)
        gemm_ln16<<<M / 16, 256, 0, stream>>>(
            ff1b, l2b + (size_t)l * D_MODEL * DFF, lin2_b + (size_t)l * D_MODEL,
            z, norm2_w + l * D_MODEL, norm2_b + l * D_MODEL, zb, DFF);
    }

    // ---- heads ----
    head_h_kernel<<<dim3(DFF / 64, 2), 256, 0, stream>>>(zb, w1b, mean_b1, lv_b1, hb);
    head_out_kernel<<<256, 256, 0, stream>>>(hb, w2b, mean_b2, lv_b2, outF);
}

// Round 12
// 417.406 us; speedup vs baseline: 1.0727x; 1.0727x over previous
//
#include <hip/hip_runtime.h>
#include <hip/hip_bf16.h>

#define D_MODEL 256
#define NHEAD 8
#define DH 32
#define NLAYERS 4
#define DFF 1024
#define CC 2
#define DATA_DIM 128
#define PP 16
#define TT 64
#define BB 4
#define LL 1024
#define NEGV -1000000.0f

typedef __bf16 bf16_t;
typedef __bf16 bf16x8 __attribute__((ext_vector_type(8)));
typedef __bf16 bf16x4 __attribute__((ext_vector_type(4)));
typedef float v4f __attribute__((ext_vector_type(4)));

__device__ __forceinline__ bool my_isnan(float v) {
    unsigned u = __float_as_uint(v);
    return (u & 0x7fffffffu) > 0x7f800000u;
}

__device__ __forceinline__ void gld16(bf16_t* l, const bf16_t* g) {
    __builtin_amdgcn_global_load_lds(
        (const __attribute__((address_space(1))) void*)g,
        (__attribute__((address_space(3))) void*)l, 16, 0, 0);
}

// ---------------------------------------------------------------------------
// Combined fp32 -> bf16 conversion, 9 weight segments, 1 dispatch
// ---------------------------------------------------------------------------
__global__ void f2b_all_kernel(const float* __restrict__ s0, bf16_t* __restrict__ d0, int n0,
                               const float* __restrict__ s1, bf16_t* __restrict__ d1, int n1,
                               const float* __restrict__ s2, bf16_t* __restrict__ d2, int n2,
                               const float* __restrict__ s3, bf16_t* __restrict__ d3, int n3,
                               const float* __restrict__ s4, bf16_t* __restrict__ d4, int n4,
                               const float* __restrict__ s5, bf16_t* __restrict__ d5, int n5,
                               const float* __restrict__ s6, bf16_t* __restrict__ d6, int n6,
                               const float* __restrict__ s7, bf16_t* __restrict__ d7, int n7,
                               const float* __restrict__ s8, bf16_t* __restrict__ d8, int n8) {
    int i = (blockIdx.x * 256 + threadIdx.x) * 4;
    const float* s;
    bf16_t* d;
    if (i < n0) { s = s0; d = d0; }
    else if ((i -= n0) < n1) { s = s1; d = d1; }
    else if ((i -= n1) < n2) { s = s2; d = d2; }
    else if ((i -= n2) < n3) { s = s3; d = d3; }
    else if ((i -= n3) < n4) { s = s4; d = d4; }
    else if ((i -= n4) < n5) { s = s5; d = d5; }
    else if ((i -= n5) < n6) { s = s6; d = d6; }
    else if ((i -= n6) < n7) { s = s7; d = d7; }
    else if ((i -= n7) < n8) { s = s8; d = d8; }
    else return;
    float4 v = *(const float4*)(s + i);
    bf16x4 o = {(bf16_t)v.x, (bf16_t)v.y, (bf16_t)v.z, (bf16_t)v.w};
    *(bf16x4*)(d + i) = o;
}

// ---------------------------------------------------------------------------
// Prep: frame_pad detection + temporal embedding MLP
// ---------------------------------------------------------------------------
__global__ void prep_frame_kernel(const float* __restrict__ img,
                                  const float* __restrict__ acq,
                                  const float* __restrict__ t_w1, const float* __restrict__ t_b1,
                                  const float* __restrict__ t_w2, const float* __restrict__ t_b2,
                                  const float* __restrict__ t_w3, const float* __restrict__ t_b3,
                                  float* __restrict__ temb, int* __restrict__ framepad) {
    int f = blockIdx.x;
    int tid = threadIdx.x;
    __shared__ float h1[64];
    __shared__ float h2[128];
    __shared__ int sAll;
    if (tid == 0) sAll = 1;
    __syncthreads();
    const float* fr = img + (size_t)f * (CC * 32 * 32);
    bool allpad = true;
    #pragma unroll
    for (int i = 0; i < 8; ++i) {
        float v = fr[tid + i * 256];
        allpad = allpad && (v == -9999.0f);
    }
    if (!allpad) sAll = 0;
    __syncthreads();
    if (tid == 0) framepad[f] = sAll;

    float t_in = acq[f];
    if (my_isnan(t_in)) t_in = 0.0f;
    if (tid < 64) h1[tid] = fmaxf(t_w1[tid] * t_in + t_b1[tid], 0.0f);
    __syncthreads();
    if (tid < 128) {
        float a = t_b2[tid];
        #pragma unroll 8
        for (int j = 0; j < 64; ++j) a += t_w2[tid * 64 + j] * h1[j];
        h2[tid] = fmaxf(a, 0.0f);
    }
    __syncthreads();
    {
        float a = t_b3[tid];
        #pragma unroll 8
        for (int j = 0; j < 128; ++j) a += t_w3[tid * 128 + j] * h2[j];
        temb[(size_t)f * D_MODEL + tid] = a;
    }
}

// ---------------------------------------------------------------------------
// Patchify: img -> xpb (bf16 4096x128), masked_rows, kmaskf.
// ---------------------------------------------------------------------------
__global__ __launch_bounds__(256) void patchify_kernel(
    const float* __restrict__ img, const float* __restrict__ nan_token,
    const int* __restrict__ framepad,
    bf16_t* __restrict__ xpb, int* __restrict__ masked_rows,
    float* __restrict__ kmaskf) {
    int tid = threadIdx.x;
    int token = blockIdx.x * 2 + (tid >> 7);
    int dd = tid & 127;
    int l = token & 1023, b = token >> 10;
    int t = l >> 4, p = l & 15;
    int c = dd >> 6, pr = (dd >> 3) & 7, pc = dd & 7;
    int hh = (p >> 2) * 8 + pr, ww = (p & 3) * 8 + pc;
    float v = img[(((size_t)(b * TT + t) * CC + c) * 32 + hh) * 32 + ww];
    bool nanp = my_isnan(v);
    if (nanp) v = fminf(fmaxf(nan_token[c], -10.0f), 10.0f);
    v = fminf(fmaxf(v, -10.0f), 10.0f);
    xpb[(size_t)token * DATA_DIM + dd] = (bf16_t)v;

    __shared__ int wAll[4];
    unsigned long long bal = __ballot(nanp);
    if ((tid & 63) == 0) wAll[tid >> 6] = (bal == 0xFFFFFFFFFFFFFFFFull) ? 1 : 0;
    __syncthreads();
    if (tid < 2) {
        int tk = blockIdx.x * 2 + tid;
        int allnan = wAll[tid * 2] & wAll[tid * 2 + 1];
        int fp = framepad[tk >> 4];
        masked_rows[tk] = allnan | fp;
        kmaskf[tk] = fp ? NEGV : 0.0f;
    }
}

// ---------------------------------------------------------------------------
// Embed GEMM: z = xp @ emb_w^T + emb_b + spatial + temb (pad override).
// ---------------------------------------------------------------------------
__global__ __launch_bounds__(256) void embed_gemm(
    const bf16_t* __restrict__ X, const bf16_t* __restrict__ W,
    const float* __restrict__ emb_b, const float* __restrict__ spatial,
    const float* __restrict__ temb, const float* __restrict__ pad_embed,
    const int* __restrict__ framepad,
    float* __restrict__ z, bf16_t* __restrict__ zb) {
    __shared__ __align__(16) bf16_t Xs[128 * 32];
    __shared__ __align__(16) bf16_t Ws[64 * 32];
    int tid = threadIdx.x;
    int wave = tid >> 6, lane = tid & 63;
    int quad = lane >> 4, l16 = lane & 15;
    int m0 = blockIdx.y * 128, n0 = blockIdx.x * 64;
    const int K = DATA_DIM, N = D_MODEL;

    v4f acc[2][4];
    #pragma unroll
    for (int i = 0; i < 2; ++i)
        #pragma unroll
        for (int j = 0; j < 4; ++j) acc[i][j] = (v4f){0.f, 0.f, 0.f, 0.f};

    int sr = tid >> 2, ss = tid & 3;
    for (int k0 = 0; k0 < K; k0 += 32) {
        gld16(Xs + tid * 8, X + (size_t)(m0 + sr) * K + k0 + ss * 8);
        gld16(Xs + 2048 + tid * 8, X + (size_t)(m0 + 64 + sr) * K + k0 + ss * 8);
        gld16(Ws + tid * 8, W + (size_t)(n0 + sr) * K + k0 + ss * 8);
        __syncthreads();
        bf16x8 af0 = *(const bf16x8*)(Xs + (wave * 32 + l16) * 32 + quad * 8);
        bf16x8 af1 = *(const bf16x8*)(Xs + (wave * 32 + 16 + l16) * 32 + quad * 8);
        #pragma unroll
        for (int nt = 0; nt < 4; ++nt) {
            bf16x8 bfr = *(const bf16x8*)(Ws + (nt * 16 + l16) * 32 + quad * 8);
            acc[0][nt] = __builtin_amdgcn_mfma_f32_16x16x32_bf16(af0, bfr, acc[0][nt], 0, 0, 0);
            acc[1][nt] = __builtin_amdgcn_mfma_f32_16x16x32_bf16(af1, bfr, acc[1][nt], 0, 0, 0);
        }
        __syncthreads();
    }

    #pragma unroll
    for (int mt = 0; mt < 2; ++mt)
        #pragma unroll
        for (int nt = 0; nt < 4; ++nt) {
            int col = n0 + nt * 16 + l16;
            #pragma unroll
            for (int reg = 0; reg < 4; ++reg) {
                int row = m0 + wave * 32 + mt * 16 + quad * 4 + reg;
                int frame = row >> 4, p = row & 15;
                float v;
                if (framepad[frame]) {
                    v = pad_embed[col];
                } else {
                    v = acc[mt][nt][reg] + emb_b[col] + spatial[p * N + col]
                      + temb[(size_t)frame * N + col];
                }
                z[(size_t)row * N + col] = v;
                zb[(size_t)row * N + col] = (bf16_t)v;
            }
        }
}

// ---------------------------------------------------------------------------
// MFMA GEMM: BM=128, BN=64, BK=64 (two 32-sub-tiles per barrier pair).
// MODE 1: bf16 out. MODE 2: qkv split. K must be divisible by 64.
// ---------------------------------------------------------------------------
template <int MODE, int RELU>
__global__ __launch_bounds__(256) void gemm_mfma(
    const bf16_t* __restrict__ X, const bf16_t* __restrict__ W,
    const float* __restrict__ bias, bf16_t* __restrict__ Y,
    bf16_t* __restrict__ Vt, int M, int N, int K) {
    __shared__ __align__(16) bf16_t Xs[2][128 * 32];
    __shared__ __align__(16) bf16_t Ws[2][64 * 32];
    int tid = threadIdx.x;
    int wave = tid >> 6, lane = tid & 63;
    int quad = lane >> 4, l16 = lane & 15;
    int m0 = blockIdx.y * 128, n0 = blockIdx.x * 64;

    v4f acc[2][4];
    #pragma unroll
    for (int i = 0; i < 2; ++i)
        #pragma unroll
        for (int j = 0; j < 4; ++j) acc[i][j] = (v4f){0.f, 0.f, 0.f, 0.f};

    int sr = tid >> 2, ss = tid & 3;
    for (int k0 = 0; k0 < K; k0 += 64) {
        #pragma unroll
        for (int half = 0; half < 2; ++half) {
            int kh = k0 + half * 32;
            gld16(Xs[half] + tid * 8, X + (size_t)(m0 + sr) * K + kh + ss * 8);
            gld16(Xs[half] + 2048 + tid * 8, X + (size_t)(m0 + 64 + sr) * K + kh + ss * 8);
            gld16(Ws[half] + tid * 8, W + (size_t)(n0 + sr) * K + kh + ss * 8);
        }
        __syncthreads();
        #pragma unroll
        for (int half = 0; half < 2; ++half) {
            bf16x8 af0 = *(const bf16x8*)(Xs[half] + (wave * 32 + l16) * 32 + quad * 8);
            bf16x8 af1 = *(const bf16x8*)(Xs[half] + (wave * 32 + 16 + l16) * 32 + quad * 8);
            #pragma unroll
            for (int nt = 0; nt < 4; ++nt) {
                bf16x8 bfr = *(const bf16x8*)(Ws[half] + (nt * 16 + l16) * 32 + quad * 8);
                acc[0][nt] = __builtin_amdgcn_mfma_f32_16x16x32_bf16(af0, bfr, acc[0][nt], 0, 0, 0);
                acc[1][nt] = __builtin_amdgcn_mfma_f32_16x16x32_bf16(af1, bfr, acc[1][nt], 0, 0, 0);
            }
        }
        __syncthreads();
    }

    if constexpr (MODE == 1) {
        #pragma unroll
        for (int mt = 0; mt < 2; ++mt)
            #pragma unroll
            for (int nt = 0; nt < 4; ++nt) {
                int col = n0 + nt * 16 + l16;
                float bv = bias[col];
                #pragma unroll
                for (int reg = 0; reg < 4; ++reg) {
                    int row = m0 + wave * 32 + mt * 16 + quad * 4 + reg;
                    float v = acc[mt][nt][reg] + bv;
                    if (RELU) v = fmaxf(v, 0.0f);
                    Y[(size_t)row * N + col] = (bf16_t)v;
                }
            }
    } else {  // MODE 2
        if (n0 < 512) {
            #pragma unroll
            for (int mt = 0; mt < 2; ++mt)
                #pragma unroll
                for (int nt = 0; nt < 4; ++nt) {
                    int col = n0 + nt * 16 + l16;
                    float bv = bias[col];
                    #pragma unroll
                    for (int reg = 0; reg < 4; ++reg) {
                        int row = m0 + wave * 32 + mt * 16 + quad * 4 + reg;
                        float v = acc[mt][nt][reg] + bv;
                        Y[(size_t)row * 768 + col] = (bf16_t)v;
                    }
                }
        } else {
            __shared__ __align__(16) bf16_t VT[64 * 136];
            #pragma unroll
            for (int mt = 0; mt < 2; ++mt)
                #pragma unroll
                for (int nt = 0; nt < 4; ++nt) {
                    int cl = nt * 16 + l16;
                    float bv = bias[n0 + cl];
                    #pragma unroll
                    for (int reg = 0; reg < 4; ++reg) {
                        int rl = wave * 32 + mt * 16 + quad * 4 + reg;
                        VT[cl * 136 + rl] = (bf16_t)(acc[mt][nt][reg] + bv);
                    }
                }
            __syncthreads();
            int b = m0 >> 10, l0m = m0 & 1023;
            int cl = tid >> 2;
            int rbase = (tid & 3) * 8;
            int cg = n0 + cl - 512;
            int h = cg >> 5, d = cg & 31;
            bf16_t* dst = Vt + (((size_t)(b * NHEAD + h)) * DH + d) * LL + l0m;
            #pragma unroll
            for (int u = 0; u < 4; ++u)
                *(uint4*)(dst + rbase + u * 32) = *(const uint4*)(VT + cl * 136 + rbase + u * 32);
        }
    }
}

// ---------------------------------------------------------------------------
// Small-N MFMA GEMM + residual: Y = X@W^T + bias + Zres (fp32 out).
// BM=64, BN=64, BK=64 (two 32-sub-tiles per barrier pair).
// ---------------------------------------------------------------------------
__global__ __launch_bounds__(256) void gemm_small(
    const bf16_t* __restrict__ X, const bf16_t* __restrict__ W,
    const float* __restrict__ bias, const float* __restrict__ Zres,
    float* __restrict__ Y, int M, int N, int K) {
    __shared__ __align__(16) bf16_t Xs[2][64 * 32];
    __shared__ __align__(16) bf16_t Ws[2][64 * 32];
    int tid = threadIdx.x;
    int wave = tid >> 6, lane = tid & 63;
    int quad = lane >> 4, l16 = lane & 15;
    int m0 = blockIdx.y * 64, n0 = blockIdx.x * 64;

    v4f acc[4];
    #pragma unroll
    for (int j = 0; j < 4; ++j) acc[j] = (v4f){0.f, 0.f, 0.f, 0.f};

    int sr = tid >> 2, ss = tid & 3;
    for (int k0 = 0; k0 < K; k0 += 64) {
        #pragma unroll
        for (int half = 0; half < 2; ++half) {
            int kh = k0 + half * 32;
            gld16(Xs[half] + tid * 8, X + (size_t)(m0 + sr) * K + kh + ss * 8);
            gld16(Ws[half] + tid * 8, W + (size_t)(n0 + sr) * K + kh + ss * 8);
        }
        __syncthreads();
        #pragma unroll
        for (int half = 0; half < 2; ++half) {
            bf16x8 af = *(const bf16x8*)(Xs[half] + (wave * 16 + l16) * 32 + quad * 8);
            #pragma unroll
            for (int nt = 0; nt < 4; ++nt) {
                bf16x8 bfr = *(const bf16x8*)(Ws[half] + (nt * 16 + l16) * 32 + quad * 8);
                acc[nt] = __builtin_amdgcn_mfma_f32_16x16x32_bf16(af, bfr, acc[nt], 0, 0, 0);
            }
        }
        __syncthreads();
    }

    #pragma unroll
    for (int nt = 0; nt < 4; ++nt) {
        int col = n0 + nt * 16 + l16;
        float bv = bias[col];
        #pragma unroll
        for (int reg = 0; reg < 4; ++reg) {
            int row = m0 + wave * 16 + quad * 4 + reg;
            Y[(size_t)row * N + col] = acc[nt][reg] + bv + Zres[(size_t)row * N + col];
        }
    }
}

// ---------------------------------------------------------------------------
// Flash attention, bf16 MFMA. Fixed-m softmax, XCD-pinned, 128-key chunks,
// LDS dbuf + register prefetch, 1 barrier/chunk.
// ---------------------------------------------------------------------------
__global__ __launch_bounds__(256) void attn_mfma(
    const bf16_t* __restrict__ qkvb, const bf16_t* __restrict__ Vt,
    const int* __restrict__ masked_rows, const float* __restrict__ kmaskf,
    bf16_t* __restrict__ Ob) {
    __shared__ __align__(16) bf16_t Ks[2][128 * 40];
    __shared__ __align__(16) bf16_t Vs[2][32 * 136];
    __shared__ __align__(16) float  Kms[2][128];
    __shared__ __align__(16) bf16_t Ps[4][16 * 136];

    int tid = threadIdx.x;
    int wave = tid >> 6, lane = tid & 63;
    int quad = lane >> 4, l16 = lane & 15;
    int bid = blockIdx.x;
    int h = bid & 7, b = (bid >> 3) & 3, qt = bid >> 5;
    int q0 = qt * 64 + wave * 16;
    const float scale = 0.17677669529663687f;

    bf16x8 qf = *(const bf16x8*)(qkvb + ((size_t)(b * LL) + q0 + l16) * 768 + h * DH + quad * 8);

    int mq[4];
    #pragma unroll
    for (int reg = 0; reg < 4; ++reg) mq[reg] = masked_rows[b * LL + q0 + quad * 4 + reg];

    float lrun[4];
    v4f oacc[2];
    #pragma unroll
    for (int reg = 0; reg < 4; ++reg) lrun[reg] = 0.0f;
    oacc[0] = (v4f){0.f, 0.f, 0.f, 0.f};
    oacc[1] = (v4f){0.f, 0.f, 0.f, 0.f};

    int kr = tid >> 1, kh = (tid & 1) * 16;
    int vd = tid >> 3, vs0 = (tid & 7) * 8;
    const bf16_t* Kbase = qkvb + (size_t)(b * LL) * 768 + 256 + h * DH;
    const bf16_t* Vbase = Vt + (((size_t)(b * NHEAD + h)) * DH) * LL;
    const float* kmbase = kmaskf + b * LL;

    uint4 ka, kb, va, vb;
    float kmg;
    #define LOADC(c)                                                            \
        do {                                                                    \
            int _k0 = (c) * 128;                                                \
            ka = *(const uint4*)(Kbase + (size_t)(_k0 + kr) * 768 + kh);        \
            kb = *(const uint4*)(Kbase + (size_t)(_k0 + kr) * 768 + kh + 8);    \
            va = *(const uint4*)(Vbase + (size_t)vd * LL + _k0 + vs0);          \
            vb = *(const uint4*)(Vbase + (size_t)vd * LL + _k0 + 64 + vs0);     \
            kmg = (tid < 128) ? kmbase[_k0 + tid] : 0.0f;                       \
        } while (0)
    #define WRITEBUF(buf)                                                       \
        do {                                                                    \
            *(uint4*)(Ks[(buf)] + kr * 40 + kh) = ka;                           \
            *(uint4*)(Ks[(buf)] + kr * 40 + kh + 8) = kb;                       \
            *(uint4*)(Vs[(buf)] + vd * 136 + vs0) = va;                         \
            *(uint4*)(Vs[(buf)] + vd * 136 + 64 + vs0) = vb;                    \
            if (tid < 128) Kms[(buf)][tid] = kmg;                               \
        } while (0)

    LOADC(0);
    WRITEBUF(0);
    LOADC(1);

    bf16_t* Pw = Ps[wave];
    for (int c = 0; c < 8; ++c) {
        __syncthreads();
        int cur = c & 1;
        if (c + 1 < 8) WRITEBUF(cur ^ 1);
        if (c + 2 < 8) LOADC(c + 2);

        int k0 = c * 128;
        const bf16_t* Kc = Ks[cur];
        const bf16_t* Vc = Vs[cur];
        const float* kmc = Kms[cur];

        v4f sf[8];
        #pragma unroll
        for (int nt = 0; nt < 8; ++nt) {
            bf16x8 kf = *(const bf16x8*)(Kc + (nt * 16 + l16) * 40 + quad * 8);
            v4f zf = (v4f){0.f, 0.f, 0.f, 0.f};
            sf[nt] = __builtin_amdgcn_mfma_f32_16x16x32_bf16(qf, kf, zf, 0, 0, 0);
        }

        #pragma unroll
        for (int nt = 0; nt < 8; ++nt) {
            int kg = k0 + nt * 16 + l16;
            float km = kmc[nt * 16 + l16];
            #pragma unroll
            for (int reg = 0; reg < 4; ++reg) {
                float v = sf[nt][reg] * scale + km;
                if (mq[reg] && (q0 + quad * 4 + reg != kg)) v += NEGV;
                float p = __expf(v);
                lrun[reg] += p;
                Pw[(quad * 4 + reg) * 136 + nt * 16 + l16] = (bf16_t)p;
            }
        }

        #pragma unroll
        for (int kt = 0; kt < 4; ++kt) {
            bf16x8 pf = *(const bf16x8*)(Pw + l16 * 136 + kt * 32 + quad * 8);
            #pragma unroll
            for (int nt2 = 0; nt2 < 2; ++nt2) {
                bf16x8 vf = *(const bf16x8*)(Vc + (nt2 * 16 + l16) * 136 + kt * 32 + quad * 8);
                oacc[nt2] = __builtin_amdgcn_mfma_f32_16x16x32_bf16(pf, vf, oacc[nt2], 0, 0, 0);
            }
        }
    }
    #undef LOADC
    #undef WRITEBUF

    #pragma unroll
    for (int off = 1; off < 16; off <<= 1)
        #pragma unroll
        for (int reg = 0; reg < 4; ++reg) lrun[reg] += __shfl_xor(lrun[reg], off);

    #pragma unroll
    for (int nt2 = 0; nt2 < 2; ++nt2)
        #pragma unroll
        for (int reg = 0; reg < 4; ++reg) {
            size_t row = (size_t)(b * LL) + q0 + quad * 4 + reg;
            Ob[row * 256 + h * DH + nt2 * 16 + l16] = (bf16_t)(oacc[nt2][reg] / lrun[reg]);
        }
}

// ---------------------------------------------------------------------------
// LayerNorm (input pre-summed in tmpf). Writes z fp32 + zb bf16.
// ---------------------------------------------------------------------------
__global__ __launch_bounds__(256) void ln_kernel(
    const float* __restrict__ tmpf, float* __restrict__ z,
    const float* __restrict__ w, const float* __restrict__ b,
    bf16_t* __restrict__ zb) {
    int wave = threadIdx.x >> 6, lane = threadIdx.x & 63;
    int row = blockIdx.x * 4 + wave;
    float4 x = ((const float4*)(tmpf + (size_t)row * D_MODEL))[lane];
    float s = x.x + x.y + x.z + x.w;
    #pragma unroll
    for (int off = 32; off > 0; off >>= 1) s += __shfl_xor(s, off);
    float mean = s * (1.0f / D_MODEL);
    float dx0 = x.x - mean, dx1 = x.y - mean, dx2 = x.z - mean, dx3 = x.w - mean;
    float sq = dx0 * dx0 + dx1 * dx1 + dx2 * dx2 + dx3 * dx3;
    #pragma unroll
    for (int off = 32; off > 0; off >>= 1) sq += __shfl_xor(sq, off);
    float inv = 1.0f / sqrtf(sq * (1.0f / D_MODEL) + 1e-5f);
    float4 wv = ((const float4*)w)[lane];
    float4 bv = ((const float4*)b)[lane];
    float4 r;
    r.x = dx0 * inv * wv.x + bv.x;
    r.y = dx1 * inv * wv.y + bv.y;
    r.z = dx2 * inv * wv.z + bv.z;
    r.w = dx3 * inv * wv.w + bv.w;
    ((float4*)(z + (size_t)row * D_MODEL))[lane] = r;
    bf16x4 rb = {(bf16_t)r.x, (bf16_t)r.y, (bf16_t)r.z, (bf16_t)r.w};
    *(bf16x4*)(zb + (size_t)row * D_MODEL + lane * 4) = rb;
}

// ---------------------------------------------------------------------------
// Head stage 1 (MFMA): both heads, grid.y = head.
// ---------------------------------------------------------------------------
__global__ __launch_bounds__(256) void head_h_kernel(
    const bf16_t* __restrict__ zb, const bf16_t* __restrict__ W1b,
    const float* __restrict__ mean_b1, const float* __restrict__ lv_b1,
    bf16_t* __restrict__ hb) {
    __shared__ __align__(16) bf16_t Xs[64 * 32];
    __shared__ __align__(16) bf16_t Ws[64 * 32];
    int tid = threadIdx.x;
    int wave = tid >> 6, lane = tid & 63;
    int quad = lane >> 4, l16 = lane & 15;
    int head = blockIdx.y;
    int n0 = blockIdx.x * 64;
    const bf16_t* W1h = W1b + (size_t)head * DFF * D_MODEL;
    const float* B1f = head ? lv_b1 : mean_b1;
    bf16_t* hbh = hb + (size_t)head * 64 * DFF;

    v4f acc[4];
    #pragma unroll
    for (int j = 0; j < 4; ++j) acc[j] = (v4f){0.f, 0.f, 0.f, 0.f};

    int sr = tid >> 2, ss = tid & 3;
    int gb = sr >> 4, gp = sr & 15;
    const bf16_t* xrow = zb + ((size_t)(gb * LL + (TT - 1) * PP + gp)) * D_MODEL;
    for (int k0 = 0; k0 < D_MODEL; k0 += 32) {
        gld16(Xs + tid * 8, xrow + k0 + ss * 8);
        gld16(Ws + tid * 8, W1h + (size_t)(n0 + sr) * D_MODEL + k0 + ss * 8);
        __syncthreads();
        bf16x8 af = *(const bf16x8*)(Xs + (wave * 16 + l16) * 32 + quad * 8);
        #pragma unroll
        for (int nt = 0; nt < 4; ++nt) {
            bf16x8 bfr = *(const bf16x8*)(Ws + (nt * 16 + l16) * 32 + quad * 8);
            acc[nt] = __builtin_amdgcn_mfma_f32_16x16x32_bf16(af, bfr, acc[nt], 0, 0, 0);
        }
        __syncthreads();
    }

    #pragma unroll
    for (int nt = 0; nt < 4; ++nt) {
        int col = n0 + nt * 16 + l16;
        float bv = B1f[col];
        #pragma unroll
        for (int reg = 0; reg < 4; ++reg) {
            int row = wave * 16 + quad * 4 + reg;
            hbh[(size_t)row * DFF + col] = (bf16_t)fmaxf(acc[nt][reg] + bv, 0.0f);
        }
    }
}

// ---------------------------------------------------------------------------
// Head stage 2: out = clip(h @ W2^T + B2) + unpatch scatter.
// ---------------------------------------------------------------------------
__global__ __launch_bounds__(256) void head_out_kernel(
    const bf16_t* __restrict__ hb, const bf16_t* __restrict__ W2b,
    const float* __restrict__ mean_b2, const float* __restrict__ lv_b2,
    float* __restrict__ out) {
    __shared__ __align__(16) bf16_t hrow[DFF];
    int tid = threadIdx.x;
    int bid = blockIdx.x;
    int head = bid >> 7, rr = (bid >> 1) & 63, half = bid & 1;
    int b = rr >> 4, p = rr & 15;

    if (tid < 128)
        *(uint4*)(hrow + tid * 8) =
            *(const uint4*)(hb + ((size_t)head * 64 + rr) * DFF + tid * 8);
    __syncthreads();

    int ol = tid >> 2, quarter = tid & 3;
    int o = half * 64 + ol;
    const bf16_t* wrow = W2b + ((size_t)head * DATA_DIM + o) * DFF + quarter * 256;
    const bf16_t* hseg = hrow + quarter * 256;
    float acc = 0.0f;
    #pragma unroll 8
    for (int j = 0; j < 32; ++j) {
        bf16x8 w = *(const bf16x8*)(wrow + j * 8);
        bf16x8 hv = *(const bf16x8*)(hseg + j * 8);
        #pragma unroll
        for (int e = 0; e < 8; ++e) acc += (float)w[e] * (float)hv[e];
    }
    acc += __shfl_xor(acc, 1);
    acc += __shfl_xor(acc, 2);
    if (quarter == 0) {
        const float* B2 = head ? lv_b2 : mean_b2;
        float hi = head ? 5.0f : 10.0f;
        float v = fminf(fmaxf(acc + B2[o], -10.0f), hi);
        int c = o >> 6;
        int pr = (o >> 3) & 7, pc = o & 7;
        int hh = (p >> 2) * 8 + pr, ww = (p & 3) * 8 + pc;
        out[(size_t)head * 8192 + ((size_t)(b * CC + c)) * 1024 + hh * 32 + ww] = v;
    }
}

// ---------------------------------------------------------------------------
extern "C" void kernel_launch(void* const* d_in, const int* in_sizes, int n_in,
                              void* d_out, int out_size, void* d_ws, size_t ws_size,
                              hipStream_t stream) {
    const float* img        = (const float*)d_in[0];
    const float* acq        = (const float*)d_in[1];
    const float* nan_token  = (const float*)d_in[2];
    const float* pad_embed  = (const float*)d_in[3];
    const float* emb_w      = (const float*)d_in[4];
    const float* emb_b      = (const float*)d_in[5];
    const float* spatial    = (const float*)d_in[6];
    const float* t_w1       = (const float*)d_in[7];
    const float* t_b1       = (const float*)d_in[8];
    const float* t_w2       = (const float*)d_in[9];
    const float* t_b2       = (const float*)d_in[10];
    const float* t_w3       = (const float*)d_in[11];
    const float* t_b3       = (const float*)d_in[12];
    const float* in_proj_w  = (const float*)d_in[13];
    const float* in_proj_b  = (const float*)d_in[14];
    const float* out_proj_w = (const float*)d_in[15];
    const float* out_proj_b = (const float*)d_in[16];
    const float* lin1_w     = (const float*)d_in[17];
    const float* lin1_b     = (const float*)d_in[18];
    const float* lin2_w     = (const float*)d_in[19];
    const float* lin2_b     = (const float*)d_in[20];
    const float* norm1_w    = (const float*)d_in[21];
    const float* norm1_b    = (const float*)d_in[22];
    const float* norm2_w    = (const float*)d_in[23];
    const float* norm2_b    = (const float*)d_in[24];
    const float* mean_w1    = (const float*)d_in[25];
    const float* mean_b1    = (const float*)d_in[26];
    const float* mean_w2    = (const float*)d_in[27];
    const float* mean_b2    = (const float*)d_in[28];
    const float* lv_w1      = (const float*)d_in[29];
    const float* lv_b1      = (const float*)d_in[30];
    const float* lv_w2      = (const float*)d_in[31];
    const float* lv_b2      = (const float*)d_in[32];

    const int M = BB * LL;   // 4096 tokens

    // ---- workspace carve-up ----
    char* wsb = (char*)d_ws;
    float* z       = (float*)wsb;                    wsb += (size_t)M * D_MODEL * 4;
    float* tmpf    = (float*)wsb;                    wsb += (size_t)M * D_MODEL * 4;
    float* temb    = (float*)wsb;                    wsb += (size_t)BB * TT * D_MODEL * 4;
    float* kmaskf  = (float*)wsb;                    wsb += M * 4;
    int* framepad  = (int*)wsb;                      wsb += BB * TT * 4;
    int* masked    = (int*)wsb;                      wsb += M * 4;
    wsb = (char*)(((uintptr_t)wsb + 255) & ~(uintptr_t)255);
    bf16_t* zb     = (bf16_t*)wsb;                   wsb += (size_t)M * D_MODEL * 2;
    bf16_t* xpb    = (bf16_t*)wsb;                   wsb += (size_t)M * DATA_DIM * 2;
    bf16_t* qkvb   = (bf16_t*)wsb;                   wsb += (size_t)M * 768 * 2;
    bf16_t* VtG    = (bf16_t*)wsb;                   wsb += (size_t)M * D_MODEL * 2;
    bf16_t* attnb  = (bf16_t*)wsb;                   wsb += (size_t)M * D_MODEL * 2;
    bf16_t* ff1b   = (bf16_t*)wsb;                   wsb += (size_t)M * DFF * 2;
    bf16_t* inb    = (bf16_t*)wsb;                   wsb += (size_t)NLAYERS * 768 * D_MODEL * 2;
    bf16_t* outb   = (bf16_t*)wsb;                   wsb += (size_t)NLAYERS * D_MODEL * D_MODEL * 2;
    bf16_t* l1b    = (bf16_t*)wsb;                   wsb += (size_t)NLAYERS * DFF * D_MODEL * 2;
    bf16_t* l2b    = (bf16_t*)wsb;                   wsb += (size_t)NLAYERS * D_MODEL * DFF * 2;
    bf16_t* embwb  = (bf16_t*)wsb;                   wsb += (size_t)D_MODEL * DATA_DIM * 2;
    bf16_t* w1b    = (bf16_t*)wsb;                   wsb += (size_t)2 * DFF * D_MODEL * 2;
    bf16_t* w2b    = (bf16_t*)wsb;                   wsb += (size_t)2 * DATA_DIM * DFF * 2;
    bf16_t* hb     = (bf16_t*)wsb;                   wsb += (size_t)2 * 64 * DFF * 2;

    float* outF = (float*)d_out;

    // ---- weight conversion (1 dispatch, 9 segments) ----
    {
        int n1 = NLAYERS * 768 * D_MODEL;
        int n2 = NLAYERS * D_MODEL * D_MODEL;
        int n3 = NLAYERS * DFF * D_MODEL;
        int n4 = NLAYERS * D_MODEL * DFF;
        int n5 = D_MODEL * DATA_DIM;
        int n6 = DFF * D_MODEL;
        int n7 = DFF * D_MODEL;
        int n8 = DATA_DIM * DFF;
        int n9 = DATA_DIM * DFF;
        int tot = n1 + n2 + n3 + n4 + n5 + n6 + n7 + n8 + n9;
        f2b_all_kernel<<<(tot / 4 + 255) / 256, 256, 0, stream>>>(
            in_proj_w, inb, n1, out_proj_w, outb, n2, lin1_w, l1b, n3,
            lin2_w, l2b, n4, emb_w, embwb, n5,
            mean_w1, w1b, n6, lv_w1, w1b + (size_t)DFF * D_MODEL, n7,
            mean_w2, w2b, n8, lv_w2, w2b + (size_t)DATA_DIM * DFF, n9);
    }

    // ---- prep + patchify + embed GEMM ----
    prep_frame_kernel<<<BB * TT, 256, 0, stream>>>(img, acq, t_w1, t_b1, t_w2, t_b2,
                                                   t_w3, t_b3, temb, framepad);
    patchify_kernel<<<M / 2, 256, 0, stream>>>(img, nan_token, framepad, xpb, masked, kmaskf);
    embed_gemm<<<dim3(D_MODEL / 64, M / 128), 256, 0, stream>>>(
        xpb, embwb, emb_b, spatial, temb, pad_embed, framepad, z, zb);

    // ---- transformer layers ----
    for (int l = 0; l < NLAYERS; ++l) {
        gemm_mfma<2, 0><<<dim3(768 / 64, M / 128), 256, 0, stream>>>(
            zb, inb + (size_t)l * 768 * D_MODEL, in_proj_b + (size_t)l * 768,
            qkvb, VtG, M, 768, D_MODEL);
        attn_mfma<<<BB * NHEAD * (LL / 64), 256, 0, stream>>>(qkvb, VtG, masked, kmaskf, attnb);
        gemm_small<<<dim3(D_MODEL / 64, M / 64), 256, 0, stream>>>(
            attnb, outb + (size_t)l * D_MODEL * D_MODEL, out_proj_b + (size_t)l * D_MODEL,
            z, tmpf, M, D_MODEL, D_MODEL);
        ln_kernel<<<M / 4, 256, 0, stream>>>(tmpf, z, norm1_w + l * D_MODEL,
                                             norm1_b + l * D_MODEL, zb);
        gemm_mfma<1, 1><<<dim3(DFF / 64, M / 128), 256, 0, stream>>>(
            zb, l1b + (size_t)l * DFF * D_MODEL, lin1_b + (size_t)l * DFF,
            ff1b, nullptr, M, DFF, D_MODEL);
        gemm_small<<<dim3(D_MODEL / 64, M / 64), 256, 0, stream>>>(
            ff1b, l2b + (size_t)l * D_MODEL * DFF, lin2_b + (size_t)l * D_MODEL,
            z, tmpf, M, D_MODEL, DFF);
        ln_kernel<<<M / 4, 256, 0, stream>>>(tmpf, z, norm2_w + l * D_MODEL,
                                             norm2_b + l * D_MODEL, zb);
    }

    // ---- heads ----
    head_h_kernel<<<dim3(DFF / 64, 2), 256, 0, stream>>>(zb, w1b, mean_b1, lv_b1, hb);
    head_out_kernel<<<256, 256, 0, stream>>>(hb, w2b, mean_b2, lv_b2, outF);
}

// Round 13
// 412.899 us; speedup vs baseline: 1.0844x; 1.0109x over previous
//
#include <hip/hip_runtime.h>
#include <hip/hip_bf16.h>

#define D_MODEL 256
#define NHEAD 8
#define DH 32
#define NLAYERS 4
#define DFF 1024
#define CC 2
#define DATA_DIM 128
#define PP 16
#define TT 64
#define BB 4
#define LL 1024
#define NEGV -1000000.0f

typedef __bf16 bf16_t;
typedef __bf16 bf16x8 __attribute__((ext_vector_type(8)));
typedef __bf16 bf16x4 __attribute__((ext_vector_type(4)));
typedef float v4f __attribute__((ext_vector_type(4)));

__device__ __forceinline__ bool my_isnan(float v) {
    unsigned u = __float_as_uint(v);
    return (u & 0x7fffffffu) > 0x7f800000u;
}

__device__ __forceinline__ void gld16(bf16_t* l, const bf16_t* g) {
    __builtin_amdgcn_global_load_lds(
        (const __attribute__((address_space(1))) void*)g,
        (__attribute__((address_space(3))) void*)l, 16, 0, 0);
}

// ---------------------------------------------------------------------------
// Combined fp32 -> bf16 conversion, 9 weight segments, 1 dispatch
// ---------------------------------------------------------------------------
__global__ void f2b_all_kernel(const float* __restrict__ s0, bf16_t* __restrict__ d0, int n0,
                               const float* __restrict__ s1, bf16_t* __restrict__ d1, int n1,
                               const float* __restrict__ s2, bf16_t* __restrict__ d2, int n2,
                               const float* __restrict__ s3, bf16_t* __restrict__ d3, int n3,
                               const float* __restrict__ s4, bf16_t* __restrict__ d4, int n4,
                               const float* __restrict__ s5, bf16_t* __restrict__ d5, int n5,
                               const float* __restrict__ s6, bf16_t* __restrict__ d6, int n6,
                               const float* __restrict__ s7, bf16_t* __restrict__ d7, int n7,
                               const float* __restrict__ s8, bf16_t* __restrict__ d8, int n8) {
    int i = (blockIdx.x * 256 + threadIdx.x) * 4;
    const float* s;
    bf16_t* d;
    if (i < n0) { s = s0; d = d0; }
    else if ((i -= n0) < n1) { s = s1; d = d1; }
    else if ((i -= n1) < n2) { s = s2; d = d2; }
    else if ((i -= n2) < n3) { s = s3; d = d3; }
    else if ((i -= n3) < n4) { s = s4; d = d4; }
    else if ((i -= n4) < n5) { s = s5; d = d5; }
    else if ((i -= n5) < n6) { s = s6; d = d6; }
    else if ((i -= n6) < n7) { s = s7; d = d7; }
    else if ((i -= n7) < n8) { s = s8; d = d8; }
    else return;
    float4 v = *(const float4*)(s + i);
    bf16x4 o = {(bf16_t)v.x, (bf16_t)v.y, (bf16_t)v.z, (bf16_t)v.w};
    *(bf16x4*)(d + i) = o;
}

// ---------------------------------------------------------------------------
// Prep: frame_pad detection + temporal embedding MLP
// ---------------------------------------------------------------------------
__global__ void prep_frame_kernel(const float* __restrict__ img,
                                  const float* __restrict__ acq,
                                  const float* __restrict__ t_w1, const float* __restrict__ t_b1,
                                  const float* __restrict__ t_w2, const float* __restrict__ t_b2,
                                  const float* __restrict__ t_w3, const float* __restrict__ t_b3,
                                  float* __restrict__ temb, int* __restrict__ framepad) {
    int f = blockIdx.x;
    int tid = threadIdx.x;
    __shared__ float h1[64];
    __shared__ float h2[128];
    __shared__ int sAll;
    if (tid == 0) sAll = 1;
    __syncthreads();
    const float* fr = img + (size_t)f * (CC * 32 * 32);
    bool allpad = true;
    #pragma unroll
    for (int i = 0; i < 8; ++i) {
        float v = fr[tid + i * 256];
        allpad = allpad && (v == -9999.0f);
    }
    if (!allpad) sAll = 0;
    __syncthreads();
    if (tid == 0) framepad[f] = sAll;

    float t_in = acq[f];
    if (my_isnan(t_in)) t_in = 0.0f;
    if (tid < 64) h1[tid] = fmaxf(t_w1[tid] * t_in + t_b1[tid], 0.0f);
    __syncthreads();
    if (tid < 128) {
        float a = t_b2[tid];
        #pragma unroll 8
        for (int j = 0; j < 64; ++j) a += t_w2[tid * 64 + j] * h1[j];
        h2[tid] = fmaxf(a, 0.0f);
    }
    __syncthreads();
    {
        float a = t_b3[tid];
        #pragma unroll 8
        for (int j = 0; j < 128; ++j) a += t_w3[tid * 128 + j] * h2[j];
        temb[(size_t)f * D_MODEL + tid] = a;
    }
}

// ---------------------------------------------------------------------------
// Patchify: img -> xpb (bf16 4096x128), masked_rows, kmaskf.
// ---------------------------------------------------------------------------
__global__ __launch_bounds__(256) void patchify_kernel(
    const float* __restrict__ img, const float* __restrict__ nan_token,
    const int* __restrict__ framepad,
    bf16_t* __restrict__ xpb, int* __restrict__ masked_rows,
    float* __restrict__ kmaskf) {
    int tid = threadIdx.x;
    int token = blockIdx.x * 2 + (tid >> 7);
    int dd = tid & 127;
    int l = token & 1023, b = token >> 10;
    int t = l >> 4, p = l & 15;
    int c = dd >> 6, pr = (dd >> 3) & 7, pc = dd & 7;
    int hh = (p >> 2) * 8 + pr, ww = (p & 3) * 8 + pc;
    float v = img[(((size_t)(b * TT + t) * CC + c) * 32 + hh) * 32 + ww];
    bool nanp = my_isnan(v);
    if (nanp) v = fminf(fmaxf(nan_token[c], -10.0f), 10.0f);
    v = fminf(fmaxf(v, -10.0f), 10.0f);
    xpb[(size_t)token * DATA_DIM + dd] = (bf16_t)v;

    __shared__ int wAll[4];
    unsigned long long bal = __ballot(nanp);
    if ((tid & 63) == 0) wAll[tid >> 6] = (bal == 0xFFFFFFFFFFFFFFFFull) ? 1 : 0;
    __syncthreads();
    if (tid < 2) {
        int tk = blockIdx.x * 2 + tid;
        int allnan = wAll[tid * 2] & wAll[tid * 2 + 1];
        int fp = framepad[tk >> 4];
        masked_rows[tk] = allnan | fp;
        kmaskf[tk] = fp ? NEGV : 0.0f;
    }
}

// ---------------------------------------------------------------------------
// Embed GEMM: z = xp @ emb_w^T + emb_b + spatial + temb (pad override).
// ---------------------------------------------------------------------------
__global__ __launch_bounds__(256) void embed_gemm(
    const bf16_t* __restrict__ X, const bf16_t* __restrict__ W,
    const float* __restrict__ emb_b, const float* __restrict__ spatial,
    const float* __restrict__ temb, const float* __restrict__ pad_embed,
    const int* __restrict__ framepad,
    float* __restrict__ z, bf16_t* __restrict__ zb) {
    __shared__ __align__(16) bf16_t Xs[128 * 32];
    __shared__ __align__(16) bf16_t Ws[64 * 32];
    int tid = threadIdx.x;
    int wave = tid >> 6, lane = tid & 63;
    int quad = lane >> 4, l16 = lane & 15;
    int m0 = blockIdx.y * 128, n0 = blockIdx.x * 64;
    const int K = DATA_DIM, N = D_MODEL;

    v4f acc[2][4];
    #pragma unroll
    for (int i = 0; i < 2; ++i)
        #pragma unroll
        for (int j = 0; j < 4; ++j) acc[i][j] = (v4f){0.f, 0.f, 0.f, 0.f};

    int sr = tid >> 2, ss = tid & 3;
    for (int k0 = 0; k0 < K; k0 += 32) {
        gld16(Xs + tid * 8, X + (size_t)(m0 + sr) * K + k0 + ss * 8);
        gld16(Xs + 2048 + tid * 8, X + (size_t)(m0 + 64 + sr) * K + k0 + ss * 8);
        gld16(Ws + tid * 8, W + (size_t)(n0 + sr) * K + k0 + ss * 8);
        __syncthreads();
        bf16x8 af0 = *(const bf16x8*)(Xs + (wave * 32 + l16) * 32 + quad * 8);
        bf16x8 af1 = *(const bf16x8*)(Xs + (wave * 32 + 16 + l16) * 32 + quad * 8);
        #pragma unroll
        for (int nt = 0; nt < 4; ++nt) {
            bf16x8 bfr = *(const bf16x8*)(Ws + (nt * 16 + l16) * 32 + quad * 8);
            acc[0][nt] = __builtin_amdgcn_mfma_f32_16x16x32_bf16(af0, bfr, acc[0][nt], 0, 0, 0);
            acc[1][nt] = __builtin_amdgcn_mfma_f32_16x16x32_bf16(af1, bfr, acc[1][nt], 0, 0, 0);
        }
        __syncthreads();
    }

    #pragma unroll
    for (int mt = 0; mt < 2; ++mt)
        #pragma unroll
        for (int nt = 0; nt < 4; ++nt) {
            int col = n0 + nt * 16 + l16;
            #pragma unroll
            for (int reg = 0; reg < 4; ++reg) {
                int row = m0 + wave * 32 + mt * 16 + quad * 4 + reg;
                int frame = row >> 4, p = row & 15;
                float v;
                if (framepad[frame]) {
                    v = pad_embed[col];
                } else {
                    v = acc[mt][nt][reg] + emb_b[col] + spatial[p * N + col]
                      + temb[(size_t)frame * N + col];
                }
                z[(size_t)row * N + col] = v;
                zb[(size_t)row * N + col] = (bf16_t)v;
            }
        }
}

// ---------------------------------------------------------------------------
// MFMA GEMM: BM=128, BN=64, BK=64 (two 32-sub-tiles per barrier pair).
// MODE 1: bf16 out. MODE 2: qkv split. K must be divisible by 64.
// ---------------------------------------------------------------------------
template <int MODE, int RELU>
__global__ __launch_bounds__(256) void gemm_mfma(
    const bf16_t* __restrict__ X, const bf16_t* __restrict__ W,
    const float* __restrict__ bias, bf16_t* __restrict__ Y,
    bf16_t* __restrict__ Vt, int M, int N, int K) {
    __shared__ __align__(16) bf16_t Xs[2][128 * 32];
    __shared__ __align__(16) bf16_t Ws[2][64 * 32];
    int tid = threadIdx.x;
    int wave = tid >> 6, lane = tid & 63;
    int quad = lane >> 4, l16 = lane & 15;
    int m0 = blockIdx.y * 128, n0 = blockIdx.x * 64;

    v4f acc[2][4];
    #pragma unroll
    for (int i = 0; i < 2; ++i)
        #pragma unroll
        for (int j = 0; j < 4; ++j) acc[i][j] = (v4f){0.f, 0.f, 0.f, 0.f};

    int sr = tid >> 2, ss = tid & 3;
    for (int k0 = 0; k0 < K; k0 += 64) {
        #pragma unroll
        for (int half = 0; half < 2; ++half) {
            int kh = k0 + half * 32;
            gld16(Xs[half] + tid * 8, X + (size_t)(m0 + sr) * K + kh + ss * 8);
            gld16(Xs[half] + 2048 + tid * 8, X + (size_t)(m0 + 64 + sr) * K + kh + ss * 8);
            gld16(Ws[half] + tid * 8, W + (size_t)(n0 + sr) * K + kh + ss * 8);
        }
        __syncthreads();
        #pragma unroll
        for (int half = 0; half < 2; ++half) {
            bf16x8 af0 = *(const bf16x8*)(Xs[half] + (wave * 32 + l16) * 32 + quad * 8);
            bf16x8 af1 = *(const bf16x8*)(Xs[half] + (wave * 32 + 16 + l16) * 32 + quad * 8);
            #pragma unroll
            for (int nt = 0; nt < 4; ++nt) {
                bf16x8 bfr = *(const bf16x8*)(Ws[half] + (nt * 16 + l16) * 32 + quad * 8);
                acc[0][nt] = __builtin_amdgcn_mfma_f32_16x16x32_bf16(af0, bfr, acc[0][nt], 0, 0, 0);
                acc[1][nt] = __builtin_amdgcn_mfma_f32_16x16x32_bf16(af1, bfr, acc[1][nt], 0, 0, 0);
            }
        }
        __syncthreads();
    }

    if constexpr (MODE == 1) {
        #pragma unroll
        for (int mt = 0; mt < 2; ++mt)
            #pragma unroll
            for (int nt = 0; nt < 4; ++nt) {
                int col = n0 + nt * 16 + l16;
                float bv = bias[col];
                #pragma unroll
                for (int reg = 0; reg < 4; ++reg) {
                    int row = m0 + wave * 32 + mt * 16 + quad * 4 + reg;
                    float v = acc[mt][nt][reg] + bv;
                    if (RELU) v = fmaxf(v, 0.0f);
                    Y[(size_t)row * N + col] = (bf16_t)v;
                }
            }
    } else {  // MODE 2
        if (n0 < 512) {
            #pragma unroll
            for (int mt = 0; mt < 2; ++mt)
                #pragma unroll
                for (int nt = 0; nt < 4; ++nt) {
                    int col = n0 + nt * 16 + l16;
                    float bv = bias[col];
                    #pragma unroll
                    for (int reg = 0; reg < 4; ++reg) {
                        int row = m0 + wave * 32 + mt * 16 + quad * 4 + reg;
                        float v = acc[mt][nt][reg] + bv;
                        Y[(size_t)row * 768 + col] = (bf16_t)v;
                    }
                }
        } else {
            __shared__ __align__(16) bf16_t VT[64 * 136];
            #pragma unroll
            for (int mt = 0; mt < 2; ++mt)
                #pragma unroll
                for (int nt = 0; nt < 4; ++nt) {
                    int cl = nt * 16 + l16;
                    float bv = bias[n0 + cl];
                    #pragma unroll
                    for (int reg = 0; reg < 4; ++reg) {
                        int rl = wave * 32 + mt * 16 + quad * 4 + reg;
                        VT[cl * 136 + rl] = (bf16_t)(acc[mt][nt][reg] + bv);
                    }
                }
            __syncthreads();
            int b = m0 >> 10, l0m = m0 & 1023;
            int cl = tid >> 2;
            int rbase = (tid & 3) * 8;
            int cg = n0 + cl - 512;
            int h = cg >> 5, d = cg & 31;
            bf16_t* dst = Vt + (((size_t)(b * NHEAD + h)) * DH + d) * LL + l0m;
            #pragma unroll
            for (int u = 0; u < 4; ++u)
                *(uint4*)(dst + rbase + u * 32) = *(const uint4*)(VT + cl * 136 + rbase + u * 32);
        }
    }
}

// ---------------------------------------------------------------------------
// Small-N MFMA GEMM + residual: Y = X@W^T + bias + Zres (fp32 out).
// BM=64, BN=64, BK=64 (two 32-sub-tiles per barrier pair).
// ---------------------------------------------------------------------------
__global__ __launch_bounds__(256) void gemm_small(
    const bf16_t* __restrict__ X, const bf16_t* __restrict__ W,
    const float* __restrict__ bias, const float* __restrict__ Zres,
    float* __restrict__ Y, int M, int N, int K) {
    __shared__ __align__(16) bf16_t Xs[2][64 * 32];
    __shared__ __align__(16) bf16_t Ws[2][64 * 32];
    int tid = threadIdx.x;
    int wave = tid >> 6, lane = tid & 63;
    int quad = lane >> 4, l16 = lane & 15;
    int m0 = blockIdx.y * 64, n0 = blockIdx.x * 64;

    v4f acc[4];
    #pragma unroll
    for (int j = 0; j < 4; ++j) acc[j] = (v4f){0.f, 0.f, 0.f, 0.f};

    int sr = tid >> 2, ss = tid & 3;
    for (int k0 = 0; k0 < K; k0 += 64) {
        #pragma unroll
        for (int half = 0; half < 2; ++half) {
            int kh = k0 + half * 32;
            gld16(Xs[half] + tid * 8, X + (size_t)(m0 + sr) * K + kh + ss * 8);
            gld16(Ws[half] + tid * 8, W + (size_t)(n0 + sr) * K + kh + ss * 8);
        }
        __syncthreads();
        #pragma unroll
        for (int half = 0; half < 2; ++half) {
            bf16x8 af = *(const bf16x8*)(Xs[half] + (wave * 16 + l16) * 32 + quad * 8);
            #pragma unroll
            for (int nt = 0; nt < 4; ++nt) {
                bf16x8 bfr = *(const bf16x8*)(Ws[half] + (nt * 16 + l16) * 32 + quad * 8);
                acc[nt] = __builtin_amdgcn_mfma_f32_16x16x32_bf16(af, bfr, acc[nt], 0, 0, 0);
            }
        }
        __syncthreads();
    }

    #pragma unroll
    for (int nt = 0; nt < 4; ++nt) {
        int col = n0 + nt * 16 + l16;
        float bv = bias[col];
        #pragma unroll
        for (int reg = 0; reg < 4; ++reg) {
            int row = m0 + wave * 16 + quad * 4 + reg;
            Y[(size_t)row * N + col] = acc[nt][reg] + bv + Zres[(size_t)row * N + col];
        }
    }
}

// ---------------------------------------------------------------------------
// Flash attention, bf16 MFMA. R13: S^T via mfma(kf,qf) -> vectorized P writes
// (bf16x4 = ds_write_b64, 8 per chunk instead of 32 b16), float4 kmask loads,
// single per-lane l accumulator (2-hop reduce). Fixed-m softmax, XCD-pinned,
// 128-key chunks, LDS dbuf + register prefetch, 1 barrier/chunk.
// ---------------------------------------------------------------------------
__global__ __launch_bounds__(256) void attn_mfma(
    const bf16_t* __restrict__ qkvb, const bf16_t* __restrict__ Vt,
    const int* __restrict__ masked_rows, const float* __restrict__ kmaskf,
    bf16_t* __restrict__ Ob) {
    __shared__ __align__(16) bf16_t Ks[2][128 * 40];
    __shared__ __align__(16) bf16_t Vs[2][32 * 136];
    __shared__ __align__(16) float  Kms[2][128];
    __shared__ __align__(16) bf16_t Ps[4][16 * 136];

    int tid = threadIdx.x;
    int wave = tid >> 6, lane = tid & 63;
    int quad = lane >> 4, l16 = lane & 15;
    int bid = blockIdx.x;
    int h = bid & 7, b = (bid >> 3) & 3, qt = bid >> 5;
    int q0 = qt * 64 + wave * 16;
    const float scale = 0.17677669529663687f;

    bf16x8 qf = *(const bf16x8*)(qkvb + ((size_t)(b * LL) + q0 + l16) * 768 + h * DH + quad * 8);

    int mq = masked_rows[b * LL + q0 + l16];   // per-lane query mask (q = q0 + l16)
    int qg = q0 + l16;

    float lrun = 0.0f;
    v4f oacc[2];
    oacc[0] = (v4f){0.f, 0.f, 0.f, 0.f};
    oacc[1] = (v4f){0.f, 0.f, 0.f, 0.f};

    int kr = tid >> 1, kh = (tid & 1) * 16;
    int vd = tid >> 3, vs0 = (tid & 7) * 8;
    const bf16_t* Kbase = qkvb + (size_t)(b * LL) * 768 + 256 + h * DH;
    const bf16_t* Vbase = Vt + (((size_t)(b * NHEAD + h)) * DH) * LL;
    const float* kmbase = kmaskf + b * LL;

    uint4 ka, kb, va, vb;
    float kmg;
    #define LOADC(c)                                                            \
        do {                                                                    \
            int _k0 = (c) * 128;                                                \
            ka = *(const uint4*)(Kbase + (size_t)(_k0 + kr) * 768 + kh);        \
            kb = *(const uint4*)(Kbase + (size_t)(_k0 + kr) * 768 + kh + 8);    \
            va = *(const uint4*)(Vbase + (size_t)vd * LL + _k0 + vs0);          \
            vb = *(const uint4*)(Vbase + (size_t)vd * LL + _k0 + 64 + vs0);     \
            kmg = (tid < 128) ? kmbase[_k0 + tid] : 0.0f;                       \
        } while (0)
    #define WRITEBUF(buf)                                                       \
        do {                                                                    \
            *(uint4*)(Ks[(buf)] + kr * 40 + kh) = ka;                           \
            *(uint4*)(Ks[(buf)] + kr * 40 + kh + 8) = kb;                       \
            *(uint4*)(Vs[(buf)] + vd * 136 + vs0) = va;                         \
            *(uint4*)(Vs[(buf)] + vd * 136 + 64 + vs0) = vb;                    \
            if (tid < 128) Kms[(buf)][tid] = kmg;                               \
        } while (0)

    LOADC(0);
    WRITEBUF(0);
    LOADC(1);

    bf16_t* Pw = Ps[wave];
    for (int c = 0; c < 8; ++c) {
        __syncthreads();
        int cur = c & 1;
        if (c + 1 < 8) WRITEBUF(cur ^ 1);
        if (c + 2 < 8) LOADC(c + 2);

        int k0 = c * 128;
        const bf16_t* Kc = Ks[cur];
        const bf16_t* Vc = Vs[cur];
        const float* kmc = Kms[cur];

        // S^T: mfma(kf, qf) -> row = k-local (quad*4+reg), col = q (l16)
        v4f sf[8];
        #pragma unroll
        for (int nt = 0; nt < 8; ++nt) {
            bf16x8 kf = *(const bf16x8*)(Kc + (nt * 16 + l16) * 40 + quad * 8);
            v4f zf = (v4f){0.f, 0.f, 0.f, 0.f};
            sf[nt] = __builtin_amdgcn_mfma_f32_16x16x32_bf16(kf, qf, zf, 0, 0, 0);
        }

        #pragma unroll
        for (int nt = 0; nt < 8; ++nt) {
            int kbase_nt = k0 + nt * 16 + quad * 4;
            float4 kmv = *(const float4*)(kmc + nt * 16 + quad * 4);
            float pv[4];
            #pragma unroll
            for (int reg = 0; reg < 4; ++reg) {
                float km = (reg == 0) ? kmv.x : (reg == 1) ? kmv.y : (reg == 2) ? kmv.z : kmv.w;
                float v = sf[nt][reg] * scale + km;
                if (mq && (qg != kbase_nt + reg)) v += NEGV;
                float p = __expf(v);
                lrun += p;
                pv[reg] = p;
            }
            bf16x4 pp = {(bf16_t)pv[0], (bf16_t)pv[1], (bf16_t)pv[2], (bf16_t)pv[3]};
            *(bf16x4*)(Pw + l16 * 136 + nt * 16 + quad * 4) = pp;
        }

        #pragma unroll
        for (int kt = 0; kt < 4; ++kt) {
            bf16x8 pf = *(const bf16x8*)(Pw + l16 * 136 + kt * 32 + quad * 8);
            #pragma unroll
            for (int nt2 = 0; nt2 < 2; ++nt2) {
                bf16x8 vf = *(const bf16x8*)(Vc + (nt2 * 16 + l16) * 136 + kt * 32 + quad * 8);
                oacc[nt2] = __builtin_amdgcn_mfma_f32_16x16x32_bf16(pf, vf, oacc[nt2], 0, 0, 0);
            }
        }
    }
    #undef LOADC
    #undef WRITEBUF

    // reduce l over quad bits (lanes with same l16), then redistribute to
    // C-layout rows (row q-local = quad*4+reg lives at source lane quad*4+reg)
    lrun += __shfl_xor(lrun, 16);
    lrun += __shfl_xor(lrun, 32);
    float lq[4];
    #pragma unroll
    for (int reg = 0; reg < 4; ++reg) lq[reg] = __shfl(lrun, quad * 4 + reg);

    #pragma unroll
    for (int nt2 = 0; nt2 < 2; ++nt2)
        #pragma unroll
        for (int reg = 0; reg < 4; ++reg) {
            size_t row = (size_t)(b * LL) + q0 + quad * 4 + reg;
            Ob[row * 256 + h * DH + nt2 * 16 + l16] = (bf16_t)(oacc[nt2][reg] / lq[reg]);
        }
}

// ---------------------------------------------------------------------------
// LayerNorm (input pre-summed in tmpf). Writes z fp32 + zb bf16.
// ---------------------------------------------------------------------------
__global__ __launch_bounds__(256) void ln_kernel(
    const float* __restrict__ tmpf, float* __restrict__ z,
    const float* __restrict__ w, const float* __restrict__ b,
    bf16_t* __restrict__ zb) {
    int wave = threadIdx.x >> 6, lane = threadIdx.x & 63;
    int row = blockIdx.x * 4 + wave;
    float4 x = ((const float4*)(tmpf + (size_t)row * D_MODEL))[lane];
    float s = x.x + x.y + x.z + x.w;
    #pragma unroll
    for (int off = 32; off > 0; off >>= 1) s += __shfl_xor(s, off);
    float mean = s * (1.0f / D_MODEL);
    float dx0 = x.x - mean, dx1 = x.y - mean, dx2 = x.z - mean, dx3 = x.w - mean;
    float sq = dx0 * dx0 + dx1 * dx1 + dx2 * dx2 + dx3 * dx3;
    #pragma unroll
    for (int off = 32; off > 0; off >>= 1) sq += __shfl_xor(sq, off);
    float inv = 1.0f / sqrtf(sq * (1.0f / D_MODEL) + 1e-5f);
    float4 wv = ((const float4*)w)[lane];
    float4 bv = ((const float4*)b)[lane];
    float4 r;
    r.x = dx0 * inv * wv.x + bv.x;
    r.y = dx1 * inv * wv.y + bv.y;
    r.z = dx2 * inv * wv.z + bv.z;
    r.w = dx3 * inv * wv.w + bv.w;
    ((float4*)(z + (size_t)row * D_MODEL))[lane] = r;
    bf16x4 rb = {(bf16_t)r.x, (bf16_t)r.y, (bf16_t)r.z, (bf16_t)r.w};
    *(bf16x4*)(zb + (size_t)row * D_MODEL + lane * 4) = rb;
}

// ---------------------------------------------------------------------------
// Head stage 1 (MFMA): both heads, grid.y = head.
// ---------------------------------------------------------------------------
__global__ __launch_bounds__(256) void head_h_kernel(
    const bf16_t* __restrict__ zb, const bf16_t* __restrict__ W1b,
    const float* __restrict__ mean_b1, const float* __restrict__ lv_b1,
    bf16_t* __restrict__ hb) {
    __shared__ __align__(16) bf16_t Xs[64 * 32];
    __shared__ __align__(16) bf16_t Ws[64 * 32];
    int tid = threadIdx.x;
    int wave = tid >> 6, lane = tid & 63;
    int quad = lane >> 4, l16 = lane & 15;
    int head = blockIdx.y;
    int n0 = blockIdx.x * 64;
    const bf16_t* W1h = W1b + (size_t)head * DFF * D_MODEL;
    const float* B1f = head ? lv_b1 : mean_b1;
    bf16_t* hbh = hb + (size_t)head * 64 * DFF;

    v4f acc[4];
    #pragma unroll
    for (int j = 0; j < 4; ++j) acc[j] = (v4f){0.f, 0.f, 0.f, 0.f};

    int sr = tid >> 2, ss = tid & 3;
    int gb = sr >> 4, gp = sr & 15;
    const bf16_t* xrow = zb + ((size_t)(gb * LL + (TT - 1) * PP + gp)) * D_MODEL;
    for (int k0 = 0; k0 < D_MODEL; k0 += 32) {
        gld16(Xs + tid * 8, xrow + k0 + ss * 8);
        gld16(Ws + tid * 8, W1h + (size_t)(n0 + sr) * D_MODEL + k0 + ss * 8);
        __syncthreads();
        bf16x8 af = *(const bf16x8*)(Xs + (wave * 16 + l16) * 32 + quad * 8);
        #pragma unroll
        for (int nt = 0; nt < 4; ++nt) {
            bf16x8 bfr = *(const bf16x8*)(Ws + (nt * 16 + l16) * 32 + quad * 8);
            acc[nt] = __builtin_amdgcn_mfma_f32_16x16x32_bf16(af, bfr, acc[nt], 0, 0, 0);
        }
        __syncthreads();
    }

    #pragma unroll
    for (int nt = 0; nt < 4; ++nt) {
        int col = n0 + nt * 16 + l16;
        float bv = B1f[col];
        #pragma unroll
        for (int reg = 0; reg < 4; ++reg) {
            int row = wave * 16 + quad * 4 + reg;
            hbh[(size_t)row * DFF + col] = (bf16_t)fmaxf(acc[nt][reg] + bv, 0.0f);
        }
    }
}

// ---------------------------------------------------------------------------
// Head stage 2: out = clip(h @ W2^T + B2) + unpatch scatter.
// ---------------------------------------------------------------------------
__global__ __launch_bounds__(256) void head_out_kernel(
    const bf16_t* __restrict__ hb, const bf16_t* __restrict__ W2b,
    const float* __restrict__ mean_b2, const float* __restrict__ lv_b2,
    float* __restrict__ out) {
    __shared__ __align__(16) bf16_t hrow[DFF];
    int tid = threadIdx.x;
    int bid = blockIdx.x;
    int head = bid >> 7, rr = (bid >> 1) & 63, half = bid & 1;
    int b = rr >> 4, p = rr & 15;

    if (tid < 128)
        *(uint4*)(hrow + tid * 8) =
            *(const uint4*)(hb + ((size_t)head * 64 + rr) * DFF + tid * 8);
    __syncthreads();

    int ol = tid >> 2, quarter = tid & 3;
    int o = half * 64 + ol;
    const bf16_t* wrow = W2b + ((size_t)head * DATA_DIM + o) * DFF + quarter * 256;
    const bf16_t* hseg = hrow + quarter * 256;
    float acc = 0.0f;
    #pragma unroll 8
    for (int j = 0; j < 32; ++j) {
        bf16x8 w = *(const bf16x8*)(wrow + j * 8);
        bf16x8 hv = *(const bf16x8*)(hseg + j * 8);
        #pragma unroll
        for (int e = 0; e < 8; ++e) acc += (float)w[e] * (float)hv[e];
    }
    acc += __shfl_xor(acc, 1);
    acc += __shfl_xor(acc, 2);
    if (quarter == 0) {
        const float* B2 = head ? lv_b2 : mean_b2;
        float hi = head ? 5.0f : 10.0f;
        float v = fminf(fmaxf(acc + B2[o], -10.0f), hi);
        int c = o >> 6;
        int pr = (o >> 3) & 7, pc = o & 7;
        int hh = (p >> 2) * 8 + pr, ww = (p & 3) * 8 + pc;
        out[(size_t)head * 8192 + ((size_t)(b * CC + c)) * 1024 + hh * 32 + ww] = v;
    }
}

// ---------------------------------------------------------------------------
extern "C" void kernel_launch(void* const* d_in, const int* in_sizes, int n_in,
                              void* d_out, int out_size, void* d_ws, size_t ws_size,
                              hipStream_t stream) {
    const float* img        = (const float*)d_in[0];
    const float* acq        = (const float*)d_in[1];
    const float* nan_token  = (const float*)d_in[2];
    const float* pad_embed  = (const float*)d_in[3];
    const float* emb_w      = (const float*)d_in[4];
    const float* emb_b      = (const float*)d_in[5];
    const float* spatial    = (const float*)d_in[6];
    const float* t_w1       = (const float*)d_in[7];
    const float* t_b1       = (const float*)d_in[8];
    const float* t_w2       = (const float*)d_in[9];
    const float* t_b2       = (const float*)d_in[10];
    const float* t_w3       = (const float*)d_in[11];
    const float* t_b3       = (const float*)d_in[12];
    const float* in_proj_w  = (const float*)d_in[13];
    const float* in_proj_b  = (const float*)d_in[14];
    const float* out_proj_w = (const float*)d_in[15];
    const float* out_proj_b = (const float*)d_in[16];
    const float* lin1_w     = (const float*)d_in[17];
    const float* lin1_b     = (const float*)d_in[18];
    const float* lin2_w     = (const float*)d_in[19];
    const float* lin2_b     = (const float*)d_in[20];
    const float* norm1_w    = (const float*)d_in[21];
    const float* norm1_b    = (const float*)d_in[22];
    const float* norm2_w    = (const float*)d_in[23];
    const float* norm2_b    = (const float*)d_in[24];
    const float* mean_w1    = (const float*)d_in[25];
    const float* mean_b1    = (const float*)d_in[26];
    const float* mean_w2    = (const float*)d_in[27];
    const float* mean_b2    = (const float*)d_in[28];
    const float* lv_w1      = (const float*)d_in[29];
    const float* lv_b1      = (const float*)d_in[30];
    const float* lv_w2      = (const float*)d_in[31];
    const float* lv_b2      = (const float*)d_in[32];

    const int M = BB * LL;   // 4096 tokens

    // ---- workspace carve-up ----
    char* wsb = (char*)d_ws;
    float* z       = (float*)wsb;                    wsb += (size_t)M * D_MODEL * 4;
    float* tmpf    = (float*)wsb;                    wsb += (size_t)M * D_MODEL * 4;
    float* temb    = (float*)wsb;                    wsb += (size_t)BB * TT * D_MODEL * 4;
    float* kmaskf  = (float*)wsb;                    wsb += M * 4;
    int* framepad  = (int*)wsb;                      wsb += BB * TT * 4;
    int* masked    = (int*)wsb;                      wsb += M * 4;
    wsb = (char*)(((uintptr_t)wsb + 255) & ~(uintptr_t)255);
    bf16_t* zb     = (bf16_t*)wsb;                   wsb += (size_t)M * D_MODEL * 2;
    bf16_t* xpb    = (bf16_t*)wsb;                   wsb += (size_t)M * DATA_DIM * 2;
    bf16_t* qkvb   = (bf16_t*)wsb;                   wsb += (size_t)M * 768 * 2;
    bf16_t* VtG    = (bf16_t*)wsb;                   wsb += (size_t)M * D_MODEL * 2;
    bf16_t* attnb  = (bf16_t*)wsb;                   wsb += (size_t)M * D_MODEL * 2;
    bf16_t* ff1b   = (bf16_t*)wsb;                   wsb += (size_t)M * DFF * 2;
    bf16_t* inb    = (bf16_t*)wsb;                   wsb += (size_t)NLAYERS * 768 * D_MODEL * 2;
    bf16_t* outb   = (bf16_t*)wsb;                   wsb += (size_t)NLAYERS * D_MODEL * D_MODEL * 2;
    bf16_t* l1b    = (bf16_t*)wsb;                   wsb += (size_t)NLAYERS * DFF * D_MODEL * 2;
    bf16_t* l2b    = (bf16_t*)wsb;                   wsb += (size_t)NLAYERS * D_MODEL * DFF * 2;
    bf16_t* embwb  = (bf16_t*)wsb;                   wsb += (size_t)D_MODEL * DATA_DIM * 2;
    bf16_t* w1b    = (bf16_t*)wsb;                   wsb += (size_t)2 * DFF * D_MODEL * 2;
    bf16_t* w2b    = (bf16_t*)wsb;                   wsb += (size_t)2 * DATA_DIM * DFF * 2;
    bf16_t* hb     = (bf16_t*)wsb;                   wsb += (size_t)2 * 64 * DFF * 2;

    float* outF = (float*)d_out;

    // ---- weight conversion (1 dispatch, 9 segments) ----
    {
        int n1 = NLAYERS * 768 * D_MODEL;
        int n2 = NLAYERS * D_MODEL * D_MODEL;
        int n3 = NLAYERS * DFF * D_MODEL;
        int n4 = NLAYERS * D_MODEL * DFF;
        int n5 = D_MODEL * DATA_DIM;
        int n6 = DFF * D_MODEL;
        int n7 = DFF * D_MODEL;
        int n8 = DATA_DIM * DFF;
        int n9 = DATA_DIM * DFF;
        int tot = n1 + n2 + n3 + n4 + n5 + n6 + n7 + n8 + n9;
        f2b_all_kernel<<<(tot / 4 + 255) / 256, 256, 0, stream>>>(
            in_proj_w, inb, n1, out_proj_w, outb, n2, lin1_w, l1b, n3,
            lin2_w, l2b, n4, emb_w, embwb, n5,
            mean_w1, w1b, n6, lv_w1, w1b + (size_t)DFF * D_MODEL, n7,
            mean_w2, w2b, n8, lv_w2, w2b + (size_t)DATA_DIM * DFF, n9);
    }

    // ---- prep + patchify + embed GEMM ----
    prep_frame_kernel<<<BB * TT, 256, 0, stream>>>(img, acq, t_w1, t_b1, t_w2, t_b2,
                                                   t_w3, t_b3, temb, framepad);
    patchify_kernel<<<M / 2, 256, 0, stream>>>(img, nan_token, framepad, xpb, masked, kmaskf);
    embed_gemm<<<dim3(D_MODEL / 64, M / 128), 256, 0, stream>>>(
        xpb, embwb, emb_b, spatial, temb, pad_embed, framepad, z, zb);

    // ---- transformer layers ----
    for (int l = 0; l < NLAYERS; ++l) {
        gemm_mfma<2, 0><<<dim3(768 / 64, M / 128), 256, 0, stream>>>(
            zb, inb + (size_t)l * 768 * D_MODEL, in_proj_b + (size_t)l * 768,
            qkvb, VtG, M, 768, D_MODEL);
        attn_mfma<<<BB * NHEAD * (LL / 64), 256, 0, stream>>>(qkvb, VtG, masked, kmaskf, attnb);
        gemm_small<<<dim3(D_MODEL / 64, M / 64), 256, 0, stream>>>(
            attnb, outb + (size_t)l * D_MODEL * D_MODEL, out_proj_b + (size_t)l * D_MODEL,
            z, tmpf, M, D_MODEL, D_MODEL);
        ln_kernel<<<M / 4, 256, 0, stream>>>(tmpf, z, norm1_w + l * D_MODEL,
                                             norm1_b + l * D_MODEL, zb);
        gemm_mfma<1, 1><<<dim3(DFF / 64, M / 128), 256, 0, stream>>>(
            zb, l1b + (size_t)l * DFF * D_MODEL, lin1_b + (size_t)l * DFF,
            ff1b, nullptr, M, DFF, D_MODEL);
        gemm_small<<<dim3(D_MODEL / 64, M / 64), 256, 0, stream>>>(
            ff1b, l2b + (size_t)l * D_MODEL * DFF, lin2_b + (size_t)l * D_MODEL,
            z, tmpf, M, D_MODEL, DFF);
        ln_kernel<<<M / 4, 256, 0, stream>>>(tmpf, z, norm2_w + l * D_MODEL,
                                             norm2_b + l * D_MODEL, zb);
    }

    // ---- heads ----
    head_h_kernel<<<dim3(DFF / 64, 2), 256, 0, stream>>>(zb, w1b, mean_b1, lv_b1, hb);
    head_out_kernel<<<256, 256, 0, stream>>>(hb, w2b, mean_b2, lv_b2, outF);
}

// Round 14
// 400.806 us; speedup vs baseline: 1.1171x; 1.0302x over previous
//
#include <hip/hip_runtime.h>
#include <hip/hip_bf16.h>

#define D_MODEL 256
#define NHEAD 8
#define DH 32
#define NLAYERS 4
#define DFF 1024
#define CC 2
#define DATA_DIM 128
#define PP 16
#define TT 64
#define BB 4
#define LL 1024
#define NEGV -1000000.0f

typedef __bf16 bf16_t;
typedef __bf16 bf16x8 __attribute__((ext_vector_type(8)));
typedef __bf16 bf16x4 __attribute__((ext_vector_type(4)));
typedef float v4f __attribute__((ext_vector_type(4)));

__device__ __forceinline__ bool my_isnan(float v) {
    unsigned u = __float_as_uint(v);
    return (u & 0x7fffffffu) > 0x7f800000u;
}

__device__ __forceinline__ void gld16(bf16_t* l, const bf16_t* g) {
    __builtin_amdgcn_global_load_lds(
        (const __attribute__((address_space(1))) void*)g,
        (__attribute__((address_space(3))) void*)l, 16, 0, 0);
}

// ---------------------------------------------------------------------------
// Combined fp32 -> bf16 conversion, 9 weight segments, 1 dispatch
// ---------------------------------------------------------------------------
__global__ void f2b_all_kernel(const float* __restrict__ s0, bf16_t* __restrict__ d0, int n0,
                               const float* __restrict__ s1, bf16_t* __restrict__ d1, int n1,
                               const float* __restrict__ s2, bf16_t* __restrict__ d2, int n2,
                               const float* __restrict__ s3, bf16_t* __restrict__ d3, int n3,
                               const float* __restrict__ s4, bf16_t* __restrict__ d4, int n4,
                               const float* __restrict__ s5, bf16_t* __restrict__ d5, int n5,
                               const float* __restrict__ s6, bf16_t* __restrict__ d6, int n6,
                               const float* __restrict__ s7, bf16_t* __restrict__ d7, int n7,
                               const float* __restrict__ s8, bf16_t* __restrict__ d8, int n8) {
    int i = (blockIdx.x * 256 + threadIdx.x) * 4;
    const float* s;
    bf16_t* d;
    if (i < n0) { s = s0; d = d0; }
    else if ((i -= n0) < n1) { s = s1; d = d1; }
    else if ((i -= n1) < n2) { s = s2; d = d2; }
    else if ((i -= n2) < n3) { s = s3; d = d3; }
    else if ((i -= n3) < n4) { s = s4; d = d4; }
    else if ((i -= n4) < n5) { s = s5; d = d5; }
    else if ((i -= n5) < n6) { s = s6; d = d6; }
    else if ((i -= n6) < n7) { s = s7; d = d7; }
    else if ((i -= n7) < n8) { s = s8; d = d8; }
    else return;
    float4 v = *(const float4*)(s + i);
    bf16x4 o = {(bf16_t)v.x, (bf16_t)v.y, (bf16_t)v.z, (bf16_t)v.w};
    *(bf16x4*)(d + i) = o;
}

// ---------------------------------------------------------------------------
// Prep: frame_pad detection + temporal embedding MLP
// ---------------------------------------------------------------------------
__global__ void prep_frame_kernel(const float* __restrict__ img,
                                  const float* __restrict__ acq,
                                  const float* __restrict__ t_w1, const float* __restrict__ t_b1,
                                  const float* __restrict__ t_w2, const float* __restrict__ t_b2,
                                  const float* __restrict__ t_w3, const float* __restrict__ t_b3,
                                  float* __restrict__ temb, int* __restrict__ framepad) {
    int f = blockIdx.x;
    int tid = threadIdx.x;
    __shared__ float h1[64];
    __shared__ float h2[128];
    __shared__ int sAll;
    if (tid == 0) sAll = 1;
    __syncthreads();
    const float* fr = img + (size_t)f * (CC * 32 * 32);
    bool allpad = true;
    #pragma unroll
    for (int i = 0; i < 8; ++i) {
        float v = fr[tid + i * 256];
        allpad = allpad && (v == -9999.0f);
    }
    if (!allpad) sAll = 0;
    __syncthreads();
    if (tid == 0) framepad[f] = sAll;

    float t_in = acq[f];
    if (my_isnan(t_in)) t_in = 0.0f;
    if (tid < 64) h1[tid] = fmaxf(t_w1[tid] * t_in + t_b1[tid], 0.0f);
    __syncthreads();
    if (tid < 128) {
        float a = t_b2[tid];
        #pragma unroll 8
        for (int j = 0; j < 64; ++j) a += t_w2[tid * 64 + j] * h1[j];
        h2[tid] = fmaxf(a, 0.0f);
    }
    __syncthreads();
    {
        float a = t_b3[tid];
        #pragma unroll 8
        for (int j = 0; j < 128; ++j) a += t_w3[tid * 128 + j] * h2[j];
        temb[(size_t)f * D_MODEL + tid] = a;
    }
}

// ---------------------------------------------------------------------------
// Patchify: img -> xpb (bf16 4096x128), masked_rows, kmaskf.
// ---------------------------------------------------------------------------
__global__ __launch_bounds__(256) void patchify_kernel(
    const float* __restrict__ img, const float* __restrict__ nan_token,
    const int* __restrict__ framepad,
    bf16_t* __restrict__ xpb, int* __restrict__ masked_rows,
    float* __restrict__ kmaskf) {
    int tid = threadIdx.x;
    int token = blockIdx.x * 2 + (tid >> 7);
    int dd = tid & 127;
    int l = token & 1023, b = token >> 10;
    int t = l >> 4, p = l & 15;
    int c = dd >> 6, pr = (dd >> 3) & 7, pc = dd & 7;
    int hh = (p >> 2) * 8 + pr, ww = (p & 3) * 8 + pc;
    float v = img[(((size_t)(b * TT + t) * CC + c) * 32 + hh) * 32 + ww];
    bool nanp = my_isnan(v);
    if (nanp) v = fminf(fmaxf(nan_token[c], -10.0f), 10.0f);
    v = fminf(fmaxf(v, -10.0f), 10.0f);
    xpb[(size_t)token * DATA_DIM + dd] = (bf16_t)v;

    __shared__ int wAll[4];
    unsigned long long bal = __ballot(nanp);
    if ((tid & 63) == 0) wAll[tid >> 6] = (bal == 0xFFFFFFFFFFFFFFFFull) ? 1 : 0;
    __syncthreads();
    if (tid < 2) {
        int tk = blockIdx.x * 2 + tid;
        int allnan = wAll[tid * 2] & wAll[tid * 2 + 1];
        int fp = framepad[tk >> 4];
        masked_rows[tk] = allnan | fp;
        kmaskf[tk] = fp ? NEGV : 0.0f;
    }
}

// ---------------------------------------------------------------------------
// Embed GEMM: zb = bf16(xp @ emb_w^T + emb_b + spatial + temb), pad override.
// ---------------------------------------------------------------------------
__global__ __launch_bounds__(256) void embed_gemm(
    const bf16_t* __restrict__ X, const bf16_t* __restrict__ W,
    const float* __restrict__ emb_b, const float* __restrict__ spatial,
    const float* __restrict__ temb, const float* __restrict__ pad_embed,
    const int* __restrict__ framepad,
    bf16_t* __restrict__ zb) {
    __shared__ __align__(16) bf16_t Xs[128 * 32];
    __shared__ __align__(16) bf16_t Ws[64 * 32];
    int tid = threadIdx.x;
    int wave = tid >> 6, lane = tid & 63;
    int quad = lane >> 4, l16 = lane & 15;
    int m0 = blockIdx.y * 128, n0 = blockIdx.x * 64;
    const int K = DATA_DIM, N = D_MODEL;

    v4f acc[2][4];
    #pragma unroll
    for (int i = 0; i < 2; ++i)
        #pragma unroll
        for (int j = 0; j < 4; ++j) acc[i][j] = (v4f){0.f, 0.f, 0.f, 0.f};

    int sr = tid >> 2, ss = tid & 3;
    for (int k0 = 0; k0 < K; k0 += 32) {
        gld16(Xs + tid * 8, X + (size_t)(m0 + sr) * K + k0 + ss * 8);
        gld16(Xs + 2048 + tid * 8, X + (size_t)(m0 + 64 + sr) * K + k0 + ss * 8);
        gld16(Ws + tid * 8, W + (size_t)(n0 + sr) * K + k0 + ss * 8);
        __syncthreads();
        bf16x8 af0 = *(const bf16x8*)(Xs + (wave * 32 + l16) * 32 + quad * 8);
        bf16x8 af1 = *(const bf16x8*)(Xs + (wave * 32 + 16 + l16) * 32 + quad * 8);
        #pragma unroll
        for (int nt = 0; nt < 4; ++nt) {
            bf16x8 bfr = *(const bf16x8*)(Ws + (nt * 16 + l16) * 32 + quad * 8);
            acc[0][nt] = __builtin_amdgcn_mfma_f32_16x16x32_bf16(af0, bfr, acc[0][nt], 0, 0, 0);
            acc[1][nt] = __builtin_amdgcn_mfma_f32_16x16x32_bf16(af1, bfr, acc[1][nt], 0, 0, 0);
        }
        __syncthreads();
    }

    #pragma unroll
    for (int mt = 0; mt < 2; ++mt)
        #pragma unroll
        for (int nt = 0; nt < 4; ++nt) {
            int col = n0 + nt * 16 + l16;
            #pragma unroll
            for (int reg = 0; reg < 4; ++reg) {
                int row = m0 + wave * 32 + mt * 16 + quad * 4 + reg;
                int frame = row >> 4, p = row & 15;
                float v;
                if (framepad[frame]) {
                    v = pad_embed[col];
                } else {
                    v = acc[mt][nt][reg] + emb_b[col] + spatial[p * N + col]
                      + temb[(size_t)frame * N + col];
                }
                zb[(size_t)row * N + col] = (bf16_t)v;
            }
        }
}

// ---------------------------------------------------------------------------
// MFMA GEMM: BM=128, BN=64, BK=64 (two 32-sub-tiles per barrier pair).
// MODE 1: bf16 out. MODE 2: qkv split. K must be divisible by 64.
// ---------------------------------------------------------------------------
template <int MODE, int RELU>
__global__ __launch_bounds__(256) void gemm_mfma(
    const bf16_t* __restrict__ X, const bf16_t* __restrict__ W,
    const float* __restrict__ bias, bf16_t* __restrict__ Y,
    bf16_t* __restrict__ Vt, int M, int N, int K) {
    __shared__ __align__(16) bf16_t Xs[2][128 * 32];
    __shared__ __align__(16) bf16_t Ws[2][64 * 32];
    int tid = threadIdx.x;
    int wave = tid >> 6, lane = tid & 63;
    int quad = lane >> 4, l16 = lane & 15;
    int m0 = blockIdx.y * 128, n0 = blockIdx.x * 64;

    v4f acc[2][4];
    #pragma unroll
    for (int i = 0; i < 2; ++i)
        #pragma unroll
        for (int j = 0; j < 4; ++j) acc[i][j] = (v4f){0.f, 0.f, 0.f, 0.f};

    int sr = tid >> 2, ss = tid & 3;
    for (int k0 = 0; k0 < K; k0 += 64) {
        #pragma unroll
        for (int half = 0; half < 2; ++half) {
            int kh = k0 + half * 32;
            gld16(Xs[half] + tid * 8, X + (size_t)(m0 + sr) * K + kh + ss * 8);
            gld16(Xs[half] + 2048 + tid * 8, X + (size_t)(m0 + 64 + sr) * K + kh + ss * 8);
            gld16(Ws[half] + tid * 8, W + (size_t)(n0 + sr) * K + kh + ss * 8);
        }
        __syncthreads();
        #pragma unroll
        for (int half = 0; half < 2; ++half) {
            bf16x8 af0 = *(const bf16x8*)(Xs[half] + (wave * 32 + l16) * 32 + quad * 8);
            bf16x8 af1 = *(const bf16x8*)(Xs[half] + (wave * 32 + 16 + l16) * 32 + quad * 8);
            #pragma unroll
            for (int nt = 0; nt < 4; ++nt) {
                bf16x8 bfr = *(const bf16x8*)(Ws[half] + (nt * 16 + l16) * 32 + quad * 8);
                acc[0][nt] = __builtin_amdgcn_mfma_f32_16x16x32_bf16(af0, bfr, acc[0][nt], 0, 0, 0);
                acc[1][nt] = __builtin_amdgcn_mfma_f32_16x16x32_bf16(af1, bfr, acc[1][nt], 0, 0, 0);
            }
        }
        __syncthreads();
    }

    if constexpr (MODE == 1) {
        #pragma unroll
        for (int mt = 0; mt < 2; ++mt)
            #pragma unroll
            for (int nt = 0; nt < 4; ++nt) {
                int col = n0 + nt * 16 + l16;
                float bv = bias[col];
                #pragma unroll
                for (int reg = 0; reg < 4; ++reg) {
                    int row = m0 + wave * 32 + mt * 16 + quad * 4 + reg;
                    float v = acc[mt][nt][reg] + bv;
                    if (RELU) v = fmaxf(v, 0.0f);
                    Y[(size_t)row * N + col] = (bf16_t)v;
                }
            }
    } else {  // MODE 2
        if (n0 < 512) {
            #pragma unroll
            for (int mt = 0; mt < 2; ++mt)
                #pragma unroll
                for (int nt = 0; nt < 4; ++nt) {
                    int col = n0 + nt * 16 + l16;
                    float bv = bias[col];
                    #pragma unroll
                    for (int reg = 0; reg < 4; ++reg) {
                        int row = m0 + wave * 32 + mt * 16 + quad * 4 + reg;
                        float v = acc[mt][nt][reg] + bv;
                        Y[(size_t)row * 768 + col] = (bf16_t)v;
                    }
                }
        } else {
            __shared__ __align__(16) bf16_t VT[64 * 136];
            #pragma unroll
            for (int mt = 0; mt < 2; ++mt)
                #pragma unroll
                for (int nt = 0; nt < 4; ++nt) {
                    int cl = nt * 16 + l16;
                    float bv = bias[n0 + cl];
                    #pragma unroll
                    for (int reg = 0; reg < 4; ++reg) {
                        int rl = wave * 32 + mt * 16 + quad * 4 + reg;
                        VT[cl * 136 + rl] = (bf16_t)(acc[mt][nt][reg] + bv);
                    }
                }
            __syncthreads();
            int b = m0 >> 10, l0m = m0 & 1023;
            int cl = tid >> 2;
            int rbase = (tid & 3) * 8;
            int cg = n0 + cl - 512;
            int h = cg >> 5, d = cg & 31;
            bf16_t* dst = Vt + (((size_t)(b * NHEAD + h)) * DH + d) * LL + l0m;
            #pragma unroll
            for (int u = 0; u < 4; ++u)
                *(uint4*)(dst + rbase + u * 32) = *(const uint4*)(VT + cl * 136 + rbase + u * 32);
        }
    }
}

// ---------------------------------------------------------------------------
// Small-N MFMA GEMM + residual: Y = bf16(X@W^T + bias + Zres), bf16 in/out.
// BM=64, BN=64, BK=64 (two 32-sub-tiles per barrier pair).
// ---------------------------------------------------------------------------
__global__ __launch_bounds__(256) void gemm_small(
    const bf16_t* __restrict__ X, const bf16_t* __restrict__ W,
    const float* __restrict__ bias, const bf16_t* __restrict__ Zres,
    bf16_t* __restrict__ Y, int M, int N, int K) {
    __shared__ __align__(16) bf16_t Xs[2][64 * 32];
    __shared__ __align__(16) bf16_t Ws[2][64 * 32];
    int tid = threadIdx.x;
    int wave = tid >> 6, lane = tid & 63;
    int quad = lane >> 4, l16 = lane & 15;
    int m0 = blockIdx.y * 64, n0 = blockIdx.x * 64;

    v4f acc[4];
    #pragma unroll
    for (int j = 0; j < 4; ++j) acc[j] = (v4f){0.f, 0.f, 0.f, 0.f};

    int sr = tid >> 2, ss = tid & 3;
    for (int k0 = 0; k0 < K; k0 += 64) {
        #pragma unroll
        for (int half = 0; half < 2; ++half) {
            int kh = k0 + half * 32;
            gld16(Xs[half] + tid * 8, X + (size_t)(m0 + sr) * K + kh + ss * 8);
            gld16(Ws[half] + tid * 8, W + (size_t)(n0 + sr) * K + kh + ss * 8);
        }
        __syncthreads();
        #pragma unroll
        for (int half = 0; half < 2; ++half) {
            bf16x8 af = *(const bf16x8*)(Xs[half] + (wave * 16 + l16) * 32 + quad * 8);
            #pragma unroll
            for (int nt = 0; nt < 4; ++nt) {
                bf16x8 bfr = *(const bf16x8*)(Ws[half] + (nt * 16 + l16) * 32 + quad * 8);
                acc[nt] = __builtin_amdgcn_mfma_f32_16x16x32_bf16(af, bfr, acc[nt], 0, 0, 0);
            }
        }
        __syncthreads();
    }

    #pragma unroll
    for (int nt = 0; nt < 4; ++nt) {
        int col = n0 + nt * 16 + l16;
        float bv = bias[col];
        #pragma unroll
        for (int reg = 0; reg < 4; ++reg) {
            int row = m0 + wave * 16 + quad * 4 + reg;
            float r = acc[nt][reg] + bv + (float)Zres[(size_t)row * N + col];
            Y[(size_t)row * N + col] = (bf16_t)r;
        }
    }
}

// ---------------------------------------------------------------------------
// Flash attention, bf16 MFMA. S^T via mfma(kf,qf), vectorized P writes,
// fixed-m softmax, XCD-pinned, 128-key chunks, LDS dbuf + register prefetch.
// ---------------------------------------------------------------------------
__global__ __launch_bounds__(256) void attn_mfma(
    const bf16_t* __restrict__ qkvb, const bf16_t* __restrict__ Vt,
    const int* __restrict__ masked_rows, const float* __restrict__ kmaskf,
    bf16_t* __restrict__ Ob) {
    __shared__ __align__(16) bf16_t Ks[2][128 * 40];
    __shared__ __align__(16) bf16_t Vs[2][32 * 136];
    __shared__ __align__(16) float  Kms[2][128];
    __shared__ __align__(16) bf16_t Ps[4][16 * 136];

    int tid = threadIdx.x;
    int wave = tid >> 6, lane = tid & 63;
    int quad = lane >> 4, l16 = lane & 15;
    int bid = blockIdx.x;
    int h = bid & 7, b = (bid >> 3) & 3, qt = bid >> 5;
    int q0 = qt * 64 + wave * 16;
    const float scale = 0.17677669529663687f;

    bf16x8 qf = *(const bf16x8*)(qkvb + ((size_t)(b * LL) + q0 + l16) * 768 + h * DH + quad * 8);

    int mq = masked_rows[b * LL + q0 + l16];
    int qg = q0 + l16;

    float lrun = 0.0f;
    v4f oacc[2];
    oacc[0] = (v4f){0.f, 0.f, 0.f, 0.f};
    oacc[1] = (v4f){0.f, 0.f, 0.f, 0.f};

    int kr = tid >> 1, kh = (tid & 1) * 16;
    int vd = tid >> 3, vs0 = (tid & 7) * 8;
    const bf16_t* Kbase = qkvb + (size_t)(b * LL) * 768 + 256 + h * DH;
    const bf16_t* Vbase = Vt + (((size_t)(b * NHEAD + h)) * DH) * LL;
    const float* kmbase = kmaskf + b * LL;

    uint4 ka, kb, va, vb;
    float kmg;
    #define LOADC(c)                                                            \
        do {                                                                    \
            int _k0 = (c) * 128;                                                \
            ka = *(const uint4*)(Kbase + (size_t)(_k0 + kr) * 768 + kh);        \
            kb = *(const uint4*)(Kbase + (size_t)(_k0 + kr) * 768 + kh + 8);    \
            va = *(const uint4*)(Vbase + (size_t)vd * LL + _k0 + vs0);          \
            vb = *(const uint4*)(Vbase + (size_t)vd * LL + _k0 + 64 + vs0);     \
            kmg = (tid < 128) ? kmbase[_k0 + tid] : 0.0f;                       \
        } while (0)
    #define WRITEBUF(buf)                                                       \
        do {                                                                    \
            *(uint4*)(Ks[(buf)] + kr * 40 + kh) = ka;                           \
            *(uint4*)(Ks[(buf)] + kr * 40 + kh + 8) = kb;                       \
            *(uint4*)(Vs[(buf)] + vd * 136 + vs0) = va;                         \
            *(uint4*)(Vs[(buf)] + vd * 136 + 64 + vs0) = vb;                    \
            if (tid < 128) Kms[(buf)][tid] = kmg;                               \
        } while (0)

    LOADC(0);
    WRITEBUF(0);
    LOADC(1);

    bf16_t* Pw = Ps[wave];
    for (int c = 0; c < 8; ++c) {
        __syncthreads();
        int cur = c & 1;
        if (c + 1 < 8) WRITEBUF(cur ^ 1);
        if (c + 2 < 8) LOADC(c + 2);

        int k0 = c * 128;
        const bf16_t* Kc = Ks[cur];
        const bf16_t* Vc = Vs[cur];
        const float* kmc = Kms[cur];

        v4f sf[8];
        #pragma unroll
        for (int nt = 0; nt < 8; ++nt) {
            bf16x8 kf = *(const bf16x8*)(Kc + (nt * 16 + l16) * 40 + quad * 8);
            v4f zf = (v4f){0.f, 0.f, 0.f, 0.f};
            sf[nt] = __builtin_amdgcn_mfma_f32_16x16x32_bf16(kf, qf, zf, 0, 0, 0);
        }

        #pragma unroll
        for (int nt = 0; nt < 8; ++nt) {
            int kbase_nt = k0 + nt * 16 + quad * 4;
            float4 kmv = *(const float4*)(kmc + nt * 16 + quad * 4);
            float pv[4];
            #pragma unroll
            for (int reg = 0; reg < 4; ++reg) {
                float km = (reg == 0) ? kmv.x : (reg == 1) ? kmv.y : (reg == 2) ? kmv.z : kmv.w;
                float v = sf[nt][reg] * scale + km;
                if (mq && (qg != kbase_nt + reg)) v += NEGV;
                float p = __expf(v);
                lrun += p;
                pv[reg] = p;
            }
            bf16x4 pp = {(bf16_t)pv[0], (bf16_t)pv[1], (bf16_t)pv[2], (bf16_t)pv[3]};
            *(bf16x4*)(Pw + l16 * 136 + nt * 16 + quad * 4) = pp;
        }

        #pragma unroll
        for (int kt = 0; kt < 4; ++kt) {
            bf16x8 pf = *(const bf16x8*)(Pw + l16 * 136 + kt * 32 + quad * 8);
            #pragma unroll
            for (int nt2 = 0; nt2 < 2; ++nt2) {
                bf16x8 vf = *(const bf16x8*)(Vc + (nt2 * 16 + l16) * 136 + kt * 32 + quad * 8);
                oacc[nt2] = __builtin_amdgcn_mfma_f32_16x16x32_bf16(pf, vf, oacc[nt2], 0, 0, 0);
            }
        }
    }
    #undef LOADC
    #undef WRITEBUF

    lrun += __shfl_xor(lrun, 16);
    lrun += __shfl_xor(lrun, 32);
    float lq[4];
    #pragma unroll
    for (int reg = 0; reg < 4; ++reg) lq[reg] = __shfl(lrun, quad * 4 + reg);

    #pragma unroll
    for (int nt2 = 0; nt2 < 2; ++nt2)
        #pragma unroll
        for (int reg = 0; reg < 4; ++reg) {
            size_t row = (size_t)(b * LL) + q0 + quad * 4 + reg;
            Ob[row * 256 + h * DH + nt2 * 16 + l16] = (bf16_t)(oacc[nt2][reg] / lq[reg]);
        }
}

// ---------------------------------------------------------------------------
// LayerNorm over bf16 pre-sum input; writes bf16 zb only.
// Wave-per-row, lane handles 4 cols.
// ---------------------------------------------------------------------------
__global__ __launch_bounds__(256) void ln_kernel(
    const bf16_t* __restrict__ tmps, const float* __restrict__ w,
    const float* __restrict__ b, bf16_t* __restrict__ zb) {
    int wave = threadIdx.x >> 6, lane = threadIdx.x & 63;
    int row = blockIdx.x * 4 + wave;
    bf16x4 xb = *(const bf16x4*)(tmps + (size_t)row * D_MODEL + lane * 4);
    float x0 = (float)xb[0], x1 = (float)xb[1], x2 = (float)xb[2], x3 = (float)xb[3];
    float s = x0 + x1 + x2 + x3;
    #pragma unroll
    for (int off = 32; off > 0; off >>= 1) s += __shfl_xor(s, off);
    float mean = s * (1.0f / D_MODEL);
    float dx0 = x0 - mean, dx1 = x1 - mean, dx2 = x2 - mean, dx3 = x3 - mean;
    float sq = dx0 * dx0 + dx1 * dx1 + dx2 * dx2 + dx3 * dx3;
    #pragma unroll
    for (int off = 32; off > 0; off >>= 1) sq += __shfl_xor(sq, off);
    float inv = 1.0f / sqrtf(sq * (1.0f / D_MODEL) + 1e-5f);
    float4 wv = ((const float4*)w)[lane];
    float4 bv = ((const float4*)b)[lane];
    bf16x4 rb = {(bf16_t)(dx0 * inv * wv.x + bv.x),
                 (bf16_t)(dx1 * inv * wv.y + bv.y),
                 (bf16_t)(dx2 * inv * wv.z + bv.z),
                 (bf16_t)(dx3 * inv * wv.w + bv.w)};
    *(bf16x4*)(zb + (size_t)row * D_MODEL + lane * 4) = rb;
}

// ---------------------------------------------------------------------------
// Head stage 1 (MFMA): both heads, grid.y = head.
// ---------------------------------------------------------------------------
__global__ __launch_bounds__(256) void head_h_kernel(
    const bf16_t* __restrict__ zb, const bf16_t* __restrict__ W1b,
    const float* __restrict__ mean_b1, const float* __restrict__ lv_b1,
    bf16_t* __restrict__ hb) {
    __shared__ __align__(16) bf16_t Xs[64 * 32];
    __shared__ __align__(16) bf16_t Ws[64 * 32];
    int tid = threadIdx.x;
    int wave = tid >> 6, lane = tid & 63;
    int quad = lane >> 4, l16 = lane & 15;
    int head = blockIdx.y;
    int n0 = blockIdx.x * 64;
    const bf16_t* W1h = W1b + (size_t)head * DFF * D_MODEL;
    const float* B1f = head ? lv_b1 : mean_b1;
    bf16_t* hbh = hb + (size_t)head * 64 * DFF;

    v4f acc[4];
    #pragma unroll
    for (int j = 0; j < 4; ++j) acc[j] = (v4f){0.f, 0.f, 0.f, 0.f};

    int sr = tid >> 2, ss = tid & 3;
    int gb = sr >> 4, gp = sr & 15;
    const bf16_t* xrow = zb + ((size_t)(gb * LL + (TT - 1) * PP + gp)) * D_MODEL;
    for (int k0 = 0; k0 < D_MODEL; k0 += 32) {
        gld16(Xs + tid * 8, xrow + k0 + ss * 8);
        gld16(Ws + tid * 8, W1h + (size_t)(n0 + sr) * D_MODEL + k0 + ss * 8);
        __syncthreads();
        bf16x8 af = *(const bf16x8*)(Xs + (wave * 16 + l16) * 32 + quad * 8);
        #pragma unroll
        for (int nt = 0; nt < 4; ++nt) {
            bf16x8 bfr = *(const bf16x8*)(Ws + (nt * 16 + l16) * 32 + quad * 8);
            acc[nt] = __builtin_amdgcn_mfma_f32_16x16x32_bf16(af, bfr, acc[nt], 0, 0, 0);
        }
        __syncthreads();
    }

    #pragma unroll
    for (int nt = 0; nt < 4; ++nt) {
        int col = n0 + nt * 16 + l16;
        float bv = B1f[col];
        #pragma unroll
        for (int reg = 0; reg < 4; ++reg) {
            int row = wave * 16 + quad * 4 + reg;
            hbh[(size_t)row * DFF + col] = (bf16_t)fmaxf(acc[nt][reg] + bv, 0.0f);
        }
    }
}

// ---------------------------------------------------------------------------
// Head stage 2: out = clip(h @ W2^T + B2) + unpatch scatter.
// ---------------------------------------------------------------------------
__global__ __launch_bounds__(256) void head_out_kernel(
    const bf16_t* __restrict__ hb, const bf16_t* __restrict__ W2b,
    const float* __restrict__ mean_b2, const float* __restrict__ lv_b2,
    float* __restrict__ out) {
    __shared__ __align__(16) bf16_t hrow[DFF];
    int tid = threadIdx.x;
    int bid = blockIdx.x;
    int head = bid >> 7, rr = (bid >> 1) & 63, half = bid & 1;
    int b = rr >> 4, p = rr & 15;

    if (tid < 128)
        *(uint4*)(hrow + tid * 8) =
            *(const uint4*)(hb + ((size_t)head * 64 + rr) * DFF + tid * 8);
    __syncthreads();

    int ol = tid >> 2, quarter = tid & 3;
    int o = half * 64 + ol;
    const bf16_t* wrow = W2b + ((size_t)head * DATA_DIM + o) * DFF + quarter * 256;
    const bf16_t* hseg = hrow + quarter * 256;
    float acc = 0.0f;
    #pragma unroll 8
    for (int j = 0; j < 32; ++j) {
        bf16x8 w = *(const bf16x8*)(wrow + j * 8);
        bf16x8 hv = *(const bf16x8*)(hseg + j * 8);
        #pragma unroll
        for (int e = 0; e < 8; ++e) acc += (float)w[e] * (float)hv[e];
    }
    acc += __shfl_xor(acc, 1);
    acc += __shfl_xor(acc, 2);
    if (quarter == 0) {
        const float* B2 = head ? lv_b2 : mean_b2;
        float hi = head ? 5.0f : 10.0f;
        float v = fminf(fmaxf(acc + B2[o], -10.0f), hi);
        int c = o >> 6;
        int pr = (o >> 3) & 7, pc = o & 7;
        int hh = (p >> 2) * 8 + pr, ww = (p & 3) * 8 + pc;
        out[(size_t)head * 8192 + ((size_t)(b * CC + c)) * 1024 + hh * 32 + ww] = v;
    }
}

// ---------------------------------------------------------------------------
extern "C" void kernel_launch(void* const* d_in, const int* in_sizes, int n_in,
                              void* d_out, int out_size, void* d_ws, size_t ws_size,
                              hipStream_t stream) {
    const float* img        = (const float*)d_in[0];
    const float* acq        = (const float*)d_in[1];
    const float* nan_token  = (const float*)d_in[2];
    const float* pad_embed  = (const float*)d_in[3];
    const float* emb_w      = (const float*)d_in[4];
    const float* emb_b      = (const float*)d_in[5];
    const float* spatial    = (const float*)d_in[6];
    const float* t_w1       = (const float*)d_in[7];
    const float* t_b1       = (const float*)d_in[8];
    const float* t_w2       = (const float*)d_in[9];
    const float* t_b2       = (const float*)d_in[10];
    const float* t_w3       = (const float*)d_in[11];
    const float* t_b3       = (const float*)d_in[12];
    const float* in_proj_w  = (const float*)d_in[13];
    const float* in_proj_b  = (const float*)d_in[14];
    const float* out_proj_w = (const float*)d_in[15];
    const float* out_proj_b = (const float*)d_in[16];
    const float* lin1_w     = (const float*)d_in[17];
    const float* lin1_b     = (const float*)d_in[18];
    const float* lin2_w     = (const float*)d_in[19];
    const float* lin2_b     = (const float*)d_in[20];
    const float* norm1_w    = (const float*)d_in[21];
    const float* norm1_b    = (const float*)d_in[22];
    const float* norm2_w    = (const float*)d_in[23];
    const float* norm2_b    = (const float*)d_in[24];
    const float* mean_w1    = (const float*)d_in[25];
    const float* mean_b1    = (const float*)d_in[26];
    const float* mean_w2    = (const float*)d_in[27];
    const float* mean_b2    = (const float*)d_in[28];
    const float* lv_w1      = (const float*)d_in[29];
    const float* lv_b1      = (const float*)d_in[30];
    const float* lv_w2      = (const float*)d_in[31];
    const float* lv_b2      = (const float*)d_in[32];

    const int M = BB * LL;   // 4096 tokens

    // ---- workspace carve-up ----
    char* wsb = (char*)d_ws;
    float* temb    = (float*)wsb;                    wsb += (size_t)BB * TT * D_MODEL * 4;
    float* kmaskf  = (float*)wsb;                    wsb += M * 4;
    int* framepad  = (int*)wsb;                      wsb += BB * TT * 4;
    int* masked    = (int*)wsb;                      wsb += M * 4;
    wsb = (char*)(((uintptr_t)wsb + 255) & ~(uintptr_t)255);
    bf16_t* zb     = (bf16_t*)wsb;                   wsb += (size_t)M * D_MODEL * 2;
    bf16_t* tmps   = (bf16_t*)wsb;                   wsb += (size_t)M * D_MODEL * 2;
    bf16_t* xpb    = (bf16_t*)wsb;                   wsb += (size_t)M * DATA_DIM * 2;
    bf16_t* qkvb   = (bf16_t*)wsb;                   wsb += (size_t)M * 768 * 2;
    bf16_t* VtG    = (bf16_t*)wsb;                   wsb += (size_t)M * D_MODEL * 2;
    bf16_t* attnb  = (bf16_t*)wsb;                   wsb += (size_t)M * D_MODEL * 2;
    bf16_t* ff1b   = (bf16_t*)wsb;                   wsb += (size_t)M * DFF * 2;
    bf16_t* inb    = (bf16_t*)wsb;                   wsb += (size_t)NLAYERS * 768 * D_MODEL * 2;
    bf16_t* outb   = (bf16_t*)wsb;                   wsb += (size_t)NLAYERS * D_MODEL * D_MODEL * 2;
    bf16_t* l1b    = (bf16_t*)wsb;                   wsb += (size_t)NLAYERS * DFF * D_MODEL * 2;
    bf16_t* l2b    = (bf16_t*)wsb;                   wsb += (size_t)NLAYERS * D_MODEL * DFF * 2;
    bf16_t* embwb  = (bf16_t*)wsb;                   wsb += (size_t)D_MODEL * DATA_DIM * 2;
    bf16_t* w1b    = (bf16_t*)wsb;                   wsb += (size_t)2 * DFF * D_MODEL * 2;
    bf16_t* w2b    = (bf16_t*)wsb;                   wsb += (size_t)2 * DATA_DIM * DFF * 2;
    bf16_t* hb     = (bf16_t*)wsb;                   wsb += (size_t)2 * 64 * DFF * 2;

    float* outF = (float*)d_out;

    // ---- weight conversion (1 dispatch, 9 segments) ----
    {
        int n1 = NLAYERS * 768 * D_MODEL;
        int n2 = NLAYERS * D_MODEL * D_MODEL;
        int n3 = NLAYERS * DFF * D_MODEL;
        int n4 = NLAYERS * D_MODEL * DFF;
        int n5 = D_MODEL * DATA_DIM;
        int n6 = DFF * D_MODEL;
        int n7 = DFF * D_MODEL;
        int n8 = DATA_DIM * DFF;
        int n9 = DATA_DIM * DFF;
        int tot = n1 + n2 + n3 + n4 + n5 + n6 + n7 + n8 + n9;
        f2b_all_kernel<<<(tot / 4 + 255) / 256, 256, 0, stream>>>(
            in_proj_w, inb, n1, out_proj_w, outb, n2, lin1_w, l1b, n3,
            lin2_w, l2b, n4, emb_w, embwb, n5,
            mean_w1, w1b, n6, lv_w1, w1b + (size_t)DFF * D_MODEL, n7,
            mean_w2, w2b, n8, lv_w2, w2b + (size_t)DATA_DIM * DFF, n9);
    }

    // ---- prep + patchify + embed GEMM ----
    prep_frame_kernel<<<BB * TT, 256, 0, stream>>>(img, acq, t_w1, t_b1, t_w2, t_b2,
                                                   t_w3, t_b3, temb, framepad);
    patchify_kernel<<<M / 2, 256, 0, stream>>>(img, nan_token, framepad, xpb, masked, kmaskf);
    embed_gemm<<<dim3(D_MODEL / 64, M / 128), 256, 0, stream>>>(
        xpb, embwb, emb_b, spatial, temb, pad_embed, framepad, zb);

    // ---- transformer layers (bf16 residual stream) ----
    for (int l = 0; l < NLAYERS; ++l) {
        gemm_mfma<2, 0><<<dim3(768 / 64, M / 128), 256, 0, stream>>>(
            zb, inb + (size_t)l * 768 * D_MODEL, in_proj_b + (size_t)l * 768,
            qkvb, VtG, M, 768, D_MODEL);
        attn_mfma<<<BB * NHEAD * (LL / 64), 256, 0, stream>>>(qkvb, VtG, masked, kmaskf, attnb);
        // out_proj + residual -> tmps (bf16)
        gemm_small<<<dim3(D_MODEL / 64, M / 64), 256, 0, stream>>>(
            attnb, outb + (size_t)l * D_MODEL * D_MODEL, out_proj_b + (size_t)l * D_MODEL,
            zb, tmps, M, D_MODEL, D_MODEL);
        ln_kernel<<<M / 4, 256, 0, stream>>>(tmps, norm1_w + l * D_MODEL,
                                             norm1_b + l * D_MODEL, zb);
        gemm_mfma<1, 1><<<dim3(DFF / 64, M / 128), 256, 0, stream>>>(
            zb, l1b + (size_t)l * DFF * D_MODEL, lin1_b + (size_t)l * DFF,
            ff1b, nullptr, M, DFF, D_MODEL);
        // ff2 + residual -> tmps (bf16)
        gemm_small<<<dim3(D_MODEL / 64, M / 64), 256, 0, stream>>>(
            ff1b, l2b + (size_t)l * D_MODEL * DFF, lin2_b + (size_t)l * D_MODEL,
            zb, tmps, M, D_MODEL, DFF);
        ln_kernel<<<M / 4, 256, 0, stream>>>(tmps, norm2_w + l * D_MODEL,
                                             norm2_b + l * D_MODEL, zb);
    }

    // ---- heads ----
    head_h_kernel<<<dim3(DFF / 64, 2), 256, 0, stream>>>(zb, w1b, mean_b1, lv_b1, hb);
    head_out_kernel<<<256, 256, 0, stream>>>(hb, w2b, mean_b2, lv_b2, outF);
}